// Round 5
// baseline (1068.079 us; speedup 1.0000x reference)
//
#include <hip/hip_runtime.h>
#include <hip/hip_bf16.h>

#define BN 32
#define CC 128
#define NN 2025
#define KK 9
#define NGROUP 4
#define CPG 32
#define GN_EPS 1e-5f
#define ROWS_TOTAL (BN * NN)   // 64800

typedef _Float16 f16;
typedef __attribute__((ext_vector_type(8))) _Float16 f16x8;
typedef __attribute__((ext_vector_type(4))) float f32x4;

#define S28 3.725290298461914e-09f   // 2^-28
#define S40 9.094947017729282e-13f   // 2^-40
#define RH  6.103515625e-05f         // 2^-14
#define RL  1.4901161193847656e-08f  // 2^-26

#define T0F 0.17f                    // survivor threshold (9th-best ~0.23, min ~0.19)
#define CAP 100                      // per-row survivor capacity (mean ~55, max ~95; overflow -> exact fallback)

// ---------------- Kernel 1: L2 normalize -> scaled f16 split, row-major [B*N][C] ----------------
__global__ __launch_bounds__(256) void k_normalize(const float* __restrict__ x,
                                                   f16* __restrict__ xh, f16* __restrict__ xl) {
    int wid  = blockIdx.x * 4 + (threadIdx.x >> 6);   // one wave per (b,n)
    int lane = threadIdx.x & 63;
    int b = wid / NN;
    int n = wid - b * NN;
    float v0 = x[(b * CC + lane) * NN + n];
    float v1 = x[(b * CC + lane + 64) * NN + n];
    float ss = v0 * v0 + v1 * v1;
#pragma unroll
    for (int off = 32; off > 0; off >>= 1) ss += __shfl_xor(ss, off);
    float s = 1.0f / fmaxf(sqrtf(ss), 1e-12f);
    v0 *= s; v1 *= s;
    float w0 = v0 * 16384.0f, w1 = v1 * 16384.0f;
    f16 h0 = (f16)w0, h1 = (f16)w1;
    f16 l0 = (f16)((w0 - (float)h0) * 4096.0f);
    f16 l1 = (f16)((w1 - (float)h1) * 4096.0f);
    size_t base = (size_t)wid * CC;
    xh[base + lane] = h0;  xh[base + lane + 64] = h1;
    xl[base + lane] = l0;  xl[base + lane + 64] = l1;
}

// top-9 insert: (value desc, index asc) ordering; order-independent tie rules
__device__ __forceinline__ void ins9(float cand, int m, float* v, int* ix,
                                     float& mv, int& mi, int& mp) {
    bool take = (cand > mv) || ((cand == mv) && (m < mi));
    if (take) {
#pragma unroll
        for (int k = 0; k < 9; ++k) if (k == mp) { v[k] = cand; ix[k] = m; }
        float nv = v[0]; int ni = ix[0]; int np = 0;
#pragma unroll
        for (int k = 1; k < 9; ++k) {
            if (v[k] < nv || (v[k] == nv && ix[k] > ni)) { nv = v[k]; ni = ix[k]; np = k; }
        }
        mv = nv; mi = ni; mp = np;
    }
}

// ---------------- Kernel 2: fused sim + top-k: MFMA + threshold compaction ----------------
// R5 occupancy-cliff fix. History:
//   R0: VGPR=56 (<=64 granule => 32-wave cap), LDS 33KB => 4 blocks/CU = 16 waves. 351us.
//   R2: macro restructure pushed VGPR 56->72 — over the 64 cliff (m69: waves/CU halve at
//       vgpr={64,128,256}) => 16-wave cap; LDS room for 6 blocks unusable. 310us.
//   R3: launch_bounds(256,8) on the ~130-VGPR pipelined body => spill (WRITE 961MB). 1050us.
//   R4: XCD swizzle: FETCH 138->16MB proven, dur unchanged => latency source not binding;
//       bottleneck is the 16-waves/CU cap (4 waves/SIMD can't hide ~220cyc L2-hit chain).
// R5: BOTH cliffs at once => 8 blocks/CU x 4 waves = 32 waves/CU, one exact round:
//   - main loop reverted to R0's simple inline-load form (demand ~56 VGPR);
//   - __launch_bounds__(256,8): VGPR cap 512/8=64 >= demand 56 => no spill (R3's spill
//     was cap-64 against the pipelined ~130-VGPR body);
//   - CAP=100 + u16 si + conflict-free strides => LDS 19.7KB (8 blocks/CU);
//   - XCD swizzle kept (L2-resident A-stream, FETCH ~16MB).
// Tripwires: VGPR must read <=64 with WRITE_SIZE ~4.6MB (ballooning => spill => revert).
__global__ __launch_bounds__(256, 8) void k_sim_topk(const f16* __restrict__ xh, const f16* __restrict__ xl,
                                                     float* __restrict__ vout, int* __restrict__ iout) {
    __shared__ float          sv[32][CAP + 1];   // stride 101 dw; 101%32=5, gcd(5,32)=1: conflict-free
    __shared__ unsigned short si[32][CAP + 2];   // stride 204B=51 dw; gcd(51%32=19,32)=1: conflict-free
    __shared__ int   cnt[32];
    __shared__ int   nbad;
    __shared__ int   badrows[32];

    // XCD batch-affinity swizzle (bijective over 2048 blocks):
    //   id&7 -> XCD slot (round-robin dispatch) -> batch b%8;
    //   consecutive ids on one XCD walk r0 within the SAME batch (A-slice stays L2-resident).
    const int id   = blockIdx.y * 64 + blockIdx.x;       // 0..2047
    const int b    = (id & 7) + 8 * (id >> 9);
    const int r0   = ((id >> 3) & 63) * 32;
    const int t    = threadIdx.x;
    const int w    = t >> 6;
    const int lane = t & 63;
    const int jr   = lane & 15;
    const int q    = lane >> 4;

    if (t < 32) cnt[t] = 0;
    if (t == 0) nbad = 0;

    // B fragments: rows r0+tile*16+jr, 4 K-steps of 32, lane's k-window = s*32 + q*8
    f16x8 bh[2][4], bl[2][4];
#pragma unroll
    for (int tile = 0; tile < 2; ++tile) {
        int rr = b * NN + min(r0 + tile * 16 + jr, NN - 1);
        const f16* pH = xh + (size_t)rr * CC;
        const f16* pL = xl + (size_t)rr * CC;
#pragma unroll
        for (int s = 0; s < 4; ++s) {
            bh[tile][s] = *(const f16x8*)(pH + s * 32 + q * 8);
            bl[tile][s] = *(const f16x8*)(pL + s * 32 + q * 8);
        }
    }
    __syncthreads();

    // Simple R0-style main loop: inline loads, no explicit pipelining (TLP from 32
    // waves/CU does the latency hiding; the macro pipeline only bought a VGPR cliff).
    for (int chunk = 0; chunk < 32; ++chunk) {
        const int mb = chunk * 64 + w * 16;                 // wave-private 16-m window
        const int marow = b * NN + min(mb + jr, NN - 1);    // A row = m-side
        const f16* aHp = xh + (size_t)marow * CC;
        const f16* aLp = xl + (size_t)marow * CC;
        f32x4 h0 = {0.f, 0.f, 0.f, 0.f}, l0 = {0.f, 0.f, 0.f, 0.f};
        f32x4 h1 = {0.f, 0.f, 0.f, 0.f}, l1 = {0.f, 0.f, 0.f, 0.f};
#pragma unroll
        for (int s = 0; s < 4; ++s) {
            f16x8 ah = *(const f16x8*)(aHp + s * 32 + q * 8);
            f16x8 al = *(const f16x8*)(aLp + s * 32 + q * 8);
            h0 = __builtin_amdgcn_mfma_f32_16x16x32_f16(ah, bh[0][s], h0, 0, 0, 0);
            l0 = __builtin_amdgcn_mfma_f32_16x16x32_f16(ah, bl[0][s], l0, 0, 0, 0);
            l0 = __builtin_amdgcn_mfma_f32_16x16x32_f16(al, bh[0][s], l0, 0, 0, 0);
            h1 = __builtin_amdgcn_mfma_f32_16x16x32_f16(ah, bh[1][s], h1, 0, 0, 0);
            l1 = __builtin_amdgcn_mfma_f32_16x16x32_f16(ah, bl[1][s], l1, 0, 0, 0);
            l1 = __builtin_amdgcn_mfma_f32_16x16x32_f16(al, bh[1][s], l1, 0, 0, 0);
        }
        // threshold compaction: m = mb + q*4 + reg; exec-masked LDS append
#pragma unroll
        for (int reg = 0; reg < 4; ++reg) {
            int m = mb + q * 4 + reg;
            float c0 = h0[reg] * S28 + l0[reg] * S40;
            if (m < NN && c0 > T0F) {
                int pos = atomicAdd(&cnt[jr], 1);
                if (pos < CAP) { sv[jr][pos] = c0; si[jr][pos] = (unsigned short)m; }
            }
            float c1 = h1[reg] * S28 + l1[reg] * S40;
            if (m < NN && c1 > T0F) {
                int pos = atomicAdd(&cnt[16 + jr], 1);
                if (pos < CAP) { sv[16 + jr][pos] = c1; si[16 + jr][pos] = (unsigned short)m; }
            }
        }
    }
    __syncthreads();

    // Pass B: exact top-9 over survivors, one thread per row
    if (t < 32) {
        int r = r0 + t;
        if (r < NN) {
            int c = cnt[t];
            if (c >= 9 && c <= CAP) {
                float fv[9]; int fi[9];
#pragma unroll
                for (int k = 0; k < 9; ++k) { fv[k] = -3.0e38f; fi[k] = 0x7fffffff; }
                float mv = -3.0e38f; int mi = 0x7fffffff; int mp = 0;
                for (int j = 0; j < c; ++j) ins9(sv[t][j], (int)si[t][j], fv, fi, mv, mi, mp);
                float s = 1e-6f;
#pragma unroll
                for (int k = 0; k < 9; ++k) s += fv[k];
                float inv = 1.0f / s;
                int base = (b * NN + r) * KK;
#pragma unroll
                for (int k = 0; k < 9; ++k) { vout[base + k] = fv[k] * inv; iout[base + k] = fi[k]; }
            } else {
                int slot = atomicAdd(&nbad, 1);
                badrows[slot] = r;
            }
        }
    }
    __syncthreads();

    // Fallback: wave 0 exactly re-solves any bad rows (expected: none)
    if (w == 0) {
        int nb = nbad;
        for (int ib = 0; ib < nb; ++ib) {
            int r = badrows[ib];
            const f16* rH = xh + ((size_t)b * NN + r) * CC;
            const f16* rL = xl + ((size_t)b * NN + r) * CC;
            float fv[9]; int fi[9];
#pragma unroll
            for (int k = 0; k < 9; ++k) { fv[k] = -3.0e38f; fi[k] = 0x7fffffff; }
            float mv = -3.0e38f; int mi = 0x7fffffff; int mp = 0;
            for (int m = lane; m < NN; m += 64) {
                const f16* mH = xh + ((size_t)b * NN + m) * CC;
                const f16* mL = xl + ((size_t)b * NN + m) * CC;
                float a1 = 0.f, a2 = 0.f;
                for (int c2 = 0; c2 < CC; ++c2) {
                    float hr = (float)rH[c2], hm = (float)mH[c2];
                    float lr = (float)rL[c2], lm = (float)mL[c2];
                    a1 += hr * hm;
                    a2 += hr * lm + lr * hm;
                }
                ins9(a1 * S28 + a2 * S40, m, fv, fi, mv, mi, mp);
            }
#pragma unroll
            for (int off = 1; off < 64; off <<= 1) {
                float pv[9]; int pi[9];
#pragma unroll
                for (int k = 0; k < 9; ++k) { pv[k] = __shfl_xor(fv[k], off); pi[k] = __shfl_xor(fi[k], off); }
#pragma unroll
                for (int k = 0; k < 9; ++k) ins9(pv[k], pi[k], fv, fi, mv, mi, mp);
            }
            if (lane == 0) {
                float s = 1e-6f;
#pragma unroll
                for (int k = 0; k < 9; ++k) s += fv[k];
                float inv = 1.0f / s;
                int base = (b * NN + r) * KK;
#pragma unroll
                for (int k = 0; k < 9; ++k) { vout[base + k] = fv[k] * inv; iout[base + k] = fi[k]; }
            }
        }
    }
}

// ---------------- Kernel 3a: GEMM out = reconstruct(xh,xl) @ w  (layer 1) ----------------
#define RST 36
__global__ __launch_bounds__(256) void k_gemm_hl(const f16* __restrict__ xh, const f16* __restrict__ xl,
                                                 const float* __restrict__ w, float* __restrict__ out) {
    __shared__ float rowsT[CC * RST];
    int t = threadIdx.x;
    int row0 = blockIdx.x * 32;
    for (int it = 0; it < 16; ++it) {
        int qq = t + it * 256;
        int c = qq & 127, r = qq >> 7;
        size_t idx = (size_t)(row0 + r) * CC + c;
        rowsT[c * RST + r] = (float)xh[idx] * RH + (float)xl[idx] * RL;
    }
    __syncthreads();
    int j = t & 127, half = t >> 7;
    float acc[16];
#pragma unroll
    for (int r = 0; r < 16; ++r) acc[r] = 0.0f;
    for (int c = 0; c < CC; ++c) {
        float wv = w[c * CC + j];
        const float4* ap = (const float4*)&rowsT[c * RST + half * 16];
        float4 a0 = ap[0], a1 = ap[1], a2 = ap[2], a3 = ap[3];
        acc[0]  += a0.x * wv; acc[1]  += a0.y * wv; acc[2]  += a0.z * wv; acc[3]  += a0.w * wv;
        acc[4]  += a1.x * wv; acc[5]  += a1.y * wv; acc[6]  += a1.z * wv; acc[7]  += a1.w * wv;
        acc[8]  += a2.x * wv; acc[9]  += a2.y * wv; acc[10] += a2.z * wv; acc[11] += a2.w * wv;
        acc[12] += a3.x * wv; acc[13] += a3.y * wv; acc[14] += a3.z * wv; acc[15] += a3.w * wv;
    }
#pragma unroll
    for (int r = 0; r < 16; ++r) out[(size_t)(row0 + half * 16 + r) * CC + j] = acc[r];
}

// ---------------- Kernel 3b: GEMM fp32 in (layer 2) ----------------
__global__ __launch_bounds__(256) void k_gemm(const float* __restrict__ in,
                                              const float* __restrict__ w,
                                              float* __restrict__ out) {
    __shared__ float rowsT[CC * RST];
    int t = threadIdx.x;
    int row0 = blockIdx.x * 32;
    for (int it = 0; it < 16; ++it) {
        int qq = t + it * 256;
        int c = qq & 127, r = qq >> 7;
        rowsT[c * RST + r] = in[(size_t)(row0 + r) * CC + c];
    }
    __syncthreads();
    int j = t & 127, half = t >> 7;
    float acc[16];
#pragma unroll
    for (int r = 0; r < 16; ++r) acc[r] = 0.0f;
    for (int c = 0; c < CC; ++c) {
        float wv = w[c * CC + j];
        const float4* ap = (const float4*)&rowsT[c * RST + half * 16];
        float4 a0 = ap[0], a1 = ap[1], a2 = ap[2], a3 = ap[3];
        acc[0]  += a0.x * wv; acc[1]  += a0.y * wv; acc[2]  += a0.z * wv; acc[3]  += a0.w * wv;
        acc[4]  += a1.x * wv; acc[5]  += a1.y * wv; acc[6]  += a1.z * wv; acc[7]  += a1.w * wv;
        acc[8]  += a2.x * wv; acc[9]  += a2.y * wv; acc[10] += a2.z * wv; acc[11] += a2.w * wv;
        acc[12] += a3.x * wv; acc[13] += a3.y * wv; acc[14] += a3.z * wv; acc[15] += a3.w * wv;
    }
#pragma unroll
    for (int r = 0; r < 16; ++r) out[(size_t)(row0 + half * 16 + r) * CC + j] = acc[r];
}

// ---------------- Kernel 4: gather + weighted sum + bias ----------------
__global__ __launch_bounds__(256) void k_gather(const float* __restrict__ xt,
                                                const float* __restrict__ v,
                                                const int* __restrict__ idx,
                                                const float* __restrict__ bias,
                                                float* __restrict__ out) {
    int t = threadIdx.x;
    int g = blockIdx.x * 2 + (t >> 7);
    int c = t & 127;
    if (g >= ROWS_TOTAL) return;
    int b = g / NN;
    int nb = b * NN;
    float acc = bias[c];
    int base = g * KK;
#pragma unroll
    for (int k = 0; k < KK; ++k) {
        int   ii = idx[base + k];
        float vv = v[base + k];
        acc += vv * xt[(size_t)(nb + ii) * CC + c];
    }
    out[(size_t)g * CC + c] = acc;
}

// ---------------- Kernel 5: GroupNorm stats per (b, group) ----------------
__global__ __launch_bounds__(256) void k_gnstats(const float* __restrict__ xin,
                                                 float* __restrict__ stats) {
    int bg = blockIdx.x; int b = bg >> 2; int gg = bg & 3;
    size_t base = (size_t)b * (NN * CC) + gg * CPG;
    float s1 = 0.f, s2 = 0.f;
    for (int i = threadIdx.x; i < NN * CPG; i += 256) {
        float x = xin[base + (size_t)(i >> 5) * CC + (i & 31)];
        s1 += x; s2 += x * x;
    }
#pragma unroll
    for (int off = 32; off > 0; off >>= 1) { s1 += __shfl_xor(s1, off); s2 += __shfl_xor(s2, off); }
    __shared__ float r1[4], r2[4];
    int w = threadIdx.x >> 6;
    if ((threadIdx.x & 63) == 0) { r1[w] = s1; r2[w] = s2; }
    __syncthreads();
    if (threadIdx.x == 0) {
        float a = r1[0] + r1[1] + r1[2] + r1[3];
        float qq = r2[0] + r2[1] + r2[2] + r2[3];
        const float inv = 1.0f / (float)(NN * CPG);
        float mean = a * inv;
        float var = qq * inv - mean * mean;
        stats[bg * 2]     = mean;
        stats[bg * 2 + 1] = rsqrtf(fmaxf(var, 0.f) + GN_EPS);
    }
}

// ---------------- Kernel 6: GN apply + SiLU (layout-preserving, fp32 out) ----------------
__global__ __launch_bounds__(256) void k_gnsilu(const float* __restrict__ xin,
                                                const float* __restrict__ stats,
                                                const float* __restrict__ gamma,
                                                const float* __restrict__ beta,
                                                float* __restrict__ out) {
    size_t e4 = ((size_t)blockIdx.x * 256 + threadIdx.x) * 4;
    int c0 = (int)(e4 & 127);
    int b  = (int)(e4 / (NN * CC));
    int gg = c0 >> 5;
    float mean = stats[(b * 4 + gg) * 2];
    float rstd = stats[(b * 4 + gg) * 2 + 1];
    float4 x = *(const float4*)&xin[e4];
    float g0 = gamma[c0], g1 = gamma[c0 + 1], g2 = gamma[c0 + 2], g3 = gamma[c0 + 3];
    float p0 = beta[c0],  p1 = beta[c0 + 1],  p2 = beta[c0 + 2],  p3 = beta[c0 + 3];
    float y0 = (x.x - mean) * rstd * g0 + p0;
    float y1 = (x.y - mean) * rstd * g1 + p1;
    float y2 = (x.z - mean) * rstd * g2 + p2;
    float y3 = (x.w - mean) * rstd * g3 + p3;
    float4 r;
    r.x = y0 / (1.0f + expf(-y0));
    r.y = y1 / (1.0f + expf(-y1));
    r.z = y2 / (1.0f + expf(-y2));
    r.w = y3 / (1.0f + expf(-y3));
    *(float4*)&out[e4] = r;
}

// ---------------- Kernel 7: GN apply + SiLU + transpose to [B][C][N], fp32 out ----------------
__global__ __launch_bounds__(256) void k_gnsilu_out(const float* __restrict__ xin,
                                                    const float* __restrict__ stats,
                                                    const float* __restrict__ gamma,
                                                    const float* __restrict__ beta,
                                                    float* __restrict__ out) {
    __shared__ float tile[32 * 65];
    int b = blockIdx.z, ct = blockIdx.y, nt = blockIdx.x;
    int c0 = ct * 32, n0 = nt * 64;
    int t = threadIdx.x;
    int cj = t & 31, ni0 = t >> 5;
    int gg = c0 >> 5;
    float mean = stats[(b * 4 + gg) * 2];
    float rstd = stats[(b * 4 + gg) * 2 + 1];
    float gm = gamma[c0 + cj];
    float bt = beta[c0 + cj];
#pragma unroll
    for (int i = 0; i < 8; ++i) {
        int n = n0 + ni0 + i * 8;
        if (n < NN) {
            float x = xin[((size_t)b * NN + n) * CC + c0 + cj];
            float y = (x - mean) * rstd * gm + bt;
            y = y / (1.0f + expf(-y));
            tile[cj * 65 + ni0 + i * 8] = y;
        }
    }
    __syncthreads();
    int nj = t & 63, ci0 = t >> 6;
#pragma unroll
    for (int i = 0; i < 8; ++i) {
        int c = ci0 + i * 4;
        int n = n0 + nj;
        if (n < NN) out[((size_t)b * CC + c0 + c) * NN + n] = tile[c * 65 + nj];
    }
}

extern "C" void kernel_launch(void* const* d_in, const int* in_sizes, int n_in,
                              void* d_out, int out_size, void* d_ws, size_t ws_size,
                              hipStream_t stream) {
    const float* x      = (const float*)d_in[0];
    const float* w1     = (const float*)d_in[1];
    const float* b1     = (const float*)d_in[2];
    const float* w2     = (const float*)d_in[3];
    const float* b2     = (const float*)d_in[4];
    const float* gamma1 = (const float*)d_in[5];
    const float* beta1  = (const float*)d_in[6];
    const float* gamma2 = (const float*)d_in[7];
    const float* beta2  = (const float*)d_in[8];
    float* out = (float*)d_out;

    const size_t BIG = (size_t)ROWS_TOTAL * CC;   // 8,294,400
    float* ws   = (float*)d_ws;
    float* bufB = ws;                              // gemm1out -> feat2 -> gath2
    f16*   xh   = (f16*)(ws + BIG);                // f16 split hi
    f16*   xl   = xh + BIG;                        // f16 split lo
    float* bufA = ws + BIG;                        // ALIASES xh/xl; first written by gather1
    float* vbuf = ws + 2 * BIG;                    // [64800*9]
    int*   ibuf = (int*)(ws + 2 * BIG + (size_t)ROWS_TOTAL * KK);
    float* stats = ws + 2 * BIG + 2 * (size_t)ROWS_TOTAL * KK;

    k_normalize<<<ROWS_TOTAL / 4, 256, 0, stream>>>(x, xh, xl);
    k_sim_topk<<<dim3(64, BN), 256, 0, stream>>>(xh, xl, vbuf, ibuf);

    // layer 1 (xh/xl last read by k_gemm_hl; bufA aliases them and is written after)
    k_gemm_hl<<<(ROWS_TOTAL + 31) / 32, 256, 0, stream>>>(xh, xl, w1, bufB);
    k_gather<<<ROWS_TOTAL / 2, 256, 0, stream>>>(bufB, vbuf, ibuf, b1, bufA);
    k_gnstats<<<BN * NGROUP, 256, 0, stream>>>(bufA, stats);
    k_gnsilu<<<(int)(BIG / 1024), 256, 0, stream>>>(bufA, stats, gamma1, beta1, bufB);

    // layer 2
    k_gemm<<<(ROWS_TOTAL + 31) / 32, 256, 0, stream>>>(bufB, w2, bufA);
    k_gather<<<ROWS_TOTAL / 2, 256, 0, stream>>>(bufA, vbuf, ibuf, b2, bufB);
    k_gnstats<<<BN * NGROUP, 256, 0, stream>>>(bufB, stats);
    k_gnsilu_out<<<dim3((NN + 63) / 64, NGROUP, BN), 256, 0, stream>>>(bufB, stats, gamma2, beta2, out);
}

// Round 6
// 1063.345 us; speedup vs baseline: 1.0045x; 1.0045x over previous
//
#include <hip/hip_runtime.h>
#include <hip/hip_bf16.h>

#define BN 32
#define CC 128
#define NN 2025
#define KK 9
#define NGROUP 4
#define CPG 32
#define GN_EPS 1e-5f
#define ROWS_TOTAL (BN * NN)   // 64800

typedef _Float16 f16;
typedef __attribute__((ext_vector_type(8))) _Float16 f16x8;
typedef __attribute__((ext_vector_type(4))) float f32x4;

#define S28 3.725290298461914e-09f   // 2^-28
#define S40 9.094947017729282e-13f   // 2^-40
#define RH  6.103515625e-05f         // 2^-14
#define RL  1.4901161193847656e-08f  // 2^-26

#define T0F 0.17f                    // survivor threshold (9th-best ~0.23, min ~0.19)
#define CAP 100                      // per-row survivor capacity (mean ~55, max ~95; overflow -> exact fallback)

// ---------------- Kernel 1: L2 normalize -> scaled f16 split, row-major [B*N][C] ----------------
__global__ __launch_bounds__(256) void k_normalize(const float* __restrict__ x,
                                                   f16* __restrict__ xh, f16* __restrict__ xl) {
    int wid  = blockIdx.x * 4 + (threadIdx.x >> 6);   // one wave per (b,n)
    int lane = threadIdx.x & 63;
    int b = wid / NN;
    int n = wid - b * NN;
    float v0 = x[(b * CC + lane) * NN + n];
    float v1 = x[(b * CC + lane + 64) * NN + n];
    float ss = v0 * v0 + v1 * v1;
#pragma unroll
    for (int off = 32; off > 0; off >>= 1) ss += __shfl_xor(ss, off);
    float s = 1.0f / fmaxf(sqrtf(ss), 1e-12f);
    v0 *= s; v1 *= s;
    float w0 = v0 * 16384.0f, w1 = v1 * 16384.0f;
    f16 h0 = (f16)w0, h1 = (f16)w1;
    f16 l0 = (f16)((w0 - (float)h0) * 4096.0f);
    f16 l1 = (f16)((w1 - (float)h1) * 4096.0f);
    size_t base = (size_t)wid * CC;
    xh[base + lane] = h0;  xh[base + lane + 64] = h1;
    xl[base + lane] = l0;  xl[base + lane + 64] = l1;
}

// top-9 insert: (value desc, index asc) ordering; order-independent tie rules
__device__ __forceinline__ void ins9(float cand, int m, float* v, int* ix,
                                     float& mv, int& mi, int& mp) {
    bool take = (cand > mv) || ((cand == mv) && (m < mi));
    if (take) {
#pragma unroll
        for (int k = 0; k < 9; ++k) if (k == mp) { v[k] = cand; ix[k] = m; }
        float nv = v[0]; int ni = ix[0]; int np = 0;
#pragma unroll
        for (int k = 1; k < 9; ++k) {
            if (v[k] < nv || (v[k] == nv && ix[k] > ni)) { nv = v[k]; ni = ix[k]; np = k; }
        }
        mv = nv; mi = ni; mp = np;
    }
}

// ---------------- Kernel 2: fused sim + top-k: MFMA + threshold compaction ----------------
// R6: register-demand restructure (no launch_bounds clamp — R3/R5 proved any min-waves
// arg splits the unified VGPR/AGPR budget and spills catastrophically).
//   Root cause from R0..R5: true per-wave register demand of the 2-tile structure is
//   ~120 regs (B-frags 16xf16x8=64 + accs + A-frags; "VGPR=56" hid ~60 AGPRs) => all
//   prior variants were capped at 16 waves/CU by the register file. Fix structurally:
//   EACH WAVE OWNS ONE 16-ROW B-TILE (tw=w&1) and a 16-m sub-window (moff=(w>>1)*16),
//   looping 64 chunks of 32 m. Budget: B 32 + acc 8 + A 8 + addr ~12 ~= 60 <= 64 cliff
//   => 8 waves/SIMD. Same MFMA count. A-traffic 2x (4.2GB) but L2-resident via the
//   kept XCD swizzle (FETCH stayed ~16MB in R4/R5). LDS 19.7KB => 8 blocks/CU; grid
//   2048 = exactly one 8-block round per CU.
// Tripwires: VGPR_Count <= 64 (65-72 => allocator overshot, expect ~R4 perf);
//            WRITE_SIZE ~4.6MB (ballooning => spill).
__global__ __launch_bounds__(256) void k_sim_topk(const f16* __restrict__ xh, const f16* __restrict__ xl,
                                                  float* __restrict__ vout, int* __restrict__ iout) {
    __shared__ float          sv[32][CAP + 1];   // stride 101 dw; 101%32=5, gcd(5,32)=1: conflict-free
    __shared__ unsigned short si[32][CAP + 2];   // stride 204B=51 dw; gcd(51%32=19,32)=1: conflict-free
    __shared__ int   cnt[32];
    __shared__ int   nbad;
    __shared__ int   badrows[32];

    // XCD batch-affinity swizzle (bijective over 2048 blocks): id&7 -> XCD slot ->
    // batch b%8; consecutive ids on one XCD walk r0 within the SAME batch.
    const int id   = blockIdx.y * 64 + blockIdx.x;       // 0..2047
    const int b    = (id & 7) + 8 * (id >> 9);
    const int r0   = ((id >> 3) & 63) * 32;
    const int t    = threadIdx.x;
    const int w    = t >> 6;
    const int lane = t & 63;
    const int jr   = lane & 15;
    const int q    = lane >> 4;
    const int tw   = w & 1;          // which 16-row B-tile this wave owns
    const int moff = (w >> 1) * 16;  // m sub-window within each 32-m chunk

    if (t < 32) cnt[t] = 0;
    if (t == 0) nbad = 0;

    // B fragments for ONE tile: rows r0 + tw*16 + jr, 4 K-steps of 32, k-window q*8
    f16x8 bh[4], bl[4];
    {
        int rr = b * NN + min(r0 + tw * 16 + jr, NN - 1);
        const f16* pH = xh + (size_t)rr * CC;
        const f16* pL = xl + (size_t)rr * CC;
#pragma unroll
        for (int s = 0; s < 4; ++s) {
            bh[s] = *(const f16x8*)(pH + s * 32 + q * 8);
            bl[s] = *(const f16x8*)(pL + s * 32 + q * 8);
        }
    }
    __syncthreads();

    // Main loop: 64 chunks x 32 m; this wave covers m = chunk*32 + moff + [0,16).
    const int rbuf = tw * 16 + jr;   // survivor buffer = output sim-row (tile-local)
    for (int chunk = 0; chunk < 64; ++chunk) {
        const int mb = chunk * 32 + moff;
        const int marow = b * NN + min(mb + jr, NN - 1);    // A row = m-side
        const f16* aHp = xh + (size_t)marow * CC;
        const f16* aLp = xl + (size_t)marow * CC;
        f32x4 h0 = {0.f, 0.f, 0.f, 0.f}, l0 = {0.f, 0.f, 0.f, 0.f};
#pragma unroll
        for (int s = 0; s < 4; ++s) {
            f16x8 ah = *(const f16x8*)(aHp + s * 32 + q * 8);
            f16x8 al = *(const f16x8*)(aLp + s * 32 + q * 8);
            h0 = __builtin_amdgcn_mfma_f32_16x16x32_f16(ah, bh[s], h0, 0, 0, 0);
            l0 = __builtin_amdgcn_mfma_f32_16x16x32_f16(ah, bl[s], l0, 0, 0, 0);
            l0 = __builtin_amdgcn_mfma_f32_16x16x32_f16(al, bh[s], l0, 0, 0, 0);
        }
        // threshold compaction: candidate (row = rbuf, m = mb + q*4 + reg)
#pragma unroll
        for (int reg = 0; reg < 4; ++reg) {
            int m = mb + q * 4 + reg;
            float c0 = h0[reg] * S28 + l0[reg] * S40;
            if (m < NN && c0 > T0F) {
                int pos = atomicAdd(&cnt[rbuf], 1);
                if (pos < CAP) { sv[rbuf][pos] = c0; si[rbuf][pos] = (unsigned short)m; }
            }
        }
    }
    __syncthreads();

    // Pass B: exact top-9 over survivors, one thread per row
    if (t < 32) {
        int r = r0 + t;
        if (r < NN) {
            int c = cnt[t];
            if (c >= 9 && c <= CAP) {
                float fv[9]; int fi[9];
#pragma unroll
                for (int k = 0; k < 9; ++k) { fv[k] = -3.0e38f; fi[k] = 0x7fffffff; }
                float mv = -3.0e38f; int mi = 0x7fffffff; int mp = 0;
                for (int j = 0; j < c; ++j) ins9(sv[t][j], (int)si[t][j], fv, fi, mv, mi, mp);
                float s = 1e-6f;
#pragma unroll
                for (int k = 0; k < 9; ++k) s += fv[k];
                float inv = 1.0f / s;
                int base = (b * NN + r) * KK;
#pragma unroll
                for (int k = 0; k < 9; ++k) { vout[base + k] = fv[k] * inv; iout[base + k] = fi[k]; }
            } else {
                int slot = atomicAdd(&nbad, 1);
                badrows[slot] = r;
            }
        }
    }
    __syncthreads();

    // Fallback: wave 0 exactly re-solves any bad rows (expected: none)
    if (w == 0) {
        int nb = nbad;
        for (int ib = 0; ib < nb; ++ib) {
            int r = badrows[ib];
            const f16* rH = xh + ((size_t)b * NN + r) * CC;
            const f16* rL = xl + ((size_t)b * NN + r) * CC;
            float fv[9]; int fi[9];
#pragma unroll
            for (int k = 0; k < 9; ++k) { fv[k] = -3.0e38f; fi[k] = 0x7fffffff; }
            float mv = -3.0e38f; int mi = 0x7fffffff; int mp = 0;
            for (int m = lane; m < NN; m += 64) {
                const f16* mH = xh + ((size_t)b * NN + m) * CC;
                const f16* mL = xl + ((size_t)b * NN + m) * CC;
                float a1 = 0.f, a2 = 0.f;
                for (int c2 = 0; c2 < CC; ++c2) {
                    float hr = (float)rH[c2], hm = (float)mH[c2];
                    float lr = (float)rL[c2], lm = (float)mL[c2];
                    a1 += hr * hm;
                    a2 += hr * lm + lr * hm;
                }
                ins9(a1 * S28 + a2 * S40, m, fv, fi, mv, mi, mp);
            }
#pragma unroll
            for (int off = 1; off < 64; off <<= 1) {
                float pv[9]; int pi[9];
#pragma unroll
                for (int k = 0; k < 9; ++k) { pv[k] = __shfl_xor(fv[k], off); pi[k] = __shfl_xor(fi[k], off); }
#pragma unroll
                for (int k = 0; k < 9; ++k) ins9(pv[k], pi[k], fv, fi, mv, mi, mp);
            }
            if (lane == 0) {
                float s = 1e-6f;
#pragma unroll
                for (int k = 0; k < 9; ++k) s += fv[k];
                float inv = 1.0f / s;
                int base = (b * NN + r) * KK;
#pragma unroll
                for (int k = 0; k < 9; ++k) { vout[base + k] = fv[k] * inv; iout[base + k] = fi[k]; }
            }
        }
    }
}

// ---------------- Kernel 3a: GEMM out = reconstruct(xh,xl) @ w  (layer 1) ----------------
#define RST 36
__global__ __launch_bounds__(256) void k_gemm_hl(const f16* __restrict__ xh, const f16* __restrict__ xl,
                                                 const float* __restrict__ w, float* __restrict__ out) {
    __shared__ float rowsT[CC * RST];
    int t = threadIdx.x;
    int row0 = blockIdx.x * 32;
    for (int it = 0; it < 16; ++it) {
        int qq = t + it * 256;
        int c = qq & 127, r = qq >> 7;
        size_t idx = (size_t)(row0 + r) * CC + c;
        rowsT[c * RST + r] = (float)xh[idx] * RH + (float)xl[idx] * RL;
    }
    __syncthreads();
    int j = t & 127, half = t >> 7;
    float acc[16];
#pragma unroll
    for (int r = 0; r < 16; ++r) acc[r] = 0.0f;
    for (int c = 0; c < CC; ++c) {
        float wv = w[c * CC + j];
        const float4* ap = (const float4*)&rowsT[c * RST + half * 16];
        float4 a0 = ap[0], a1 = ap[1], a2 = ap[2], a3 = ap[3];
        acc[0]  += a0.x * wv; acc[1]  += a0.y * wv; acc[2]  += a0.z * wv; acc[3]  += a0.w * wv;
        acc[4]  += a1.x * wv; acc[5]  += a1.y * wv; acc[6]  += a1.z * wv; acc[7]  += a1.w * wv;
        acc[8]  += a2.x * wv; acc[9]  += a2.y * wv; acc[10] += a2.z * wv; acc[11] += a2.w * wv;
        acc[12] += a3.x * wv; acc[13] += a3.y * wv; acc[14] += a3.z * wv; acc[15] += a3.w * wv;
    }
#pragma unroll
    for (int r = 0; r < 16; ++r) out[(size_t)(row0 + half * 16 + r) * CC + j] = acc[r];
}

// ---------------- Kernel 3b: GEMM fp32 in (layer 2) ----------------
__global__ __launch_bounds__(256) void k_gemm(const float* __restrict__ in,
                                              const float* __restrict__ w,
                                              float* __restrict__ out) {
    __shared__ float rowsT[CC * RST];
    int t = threadIdx.x;
    int row0 = blockIdx.x * 32;
    for (int it = 0; it < 16; ++it) {
        int qq = t + it * 256;
        int c = qq & 127, r = qq >> 7;
        rowsT[c * RST + r] = in[(size_t)(row0 + r) * CC + c];
    }
    __syncthreads();
    int j = t & 127, half = t >> 7;
    float acc[16];
#pragma unroll
    for (int r = 0; r < 16; ++r) acc[r] = 0.0f;
    for (int c = 0; c < CC; ++c) {
        float wv = w[c * CC + j];
        const float4* ap = (const float4*)&rowsT[c * RST + half * 16];
        float4 a0 = ap[0], a1 = ap[1], a2 = ap[2], a3 = ap[3];
        acc[0]  += a0.x * wv; acc[1]  += a0.y * wv; acc[2]  += a0.z * wv; acc[3]  += a0.w * wv;
        acc[4]  += a1.x * wv; acc[5]  += a1.y * wv; acc[6]  += a1.z * wv; acc[7]  += a1.w * wv;
        acc[8]  += a2.x * wv; acc[9]  += a2.y * wv; acc[10] += a2.z * wv; acc[11] += a2.w * wv;
        acc[12] += a3.x * wv; acc[13] += a3.y * wv; acc[14] += a3.z * wv; acc[15] += a3.w * wv;
    }
#pragma unroll
    for (int r = 0; r < 16; ++r) out[(size_t)(row0 + half * 16 + r) * CC + j] = acc[r];
}

// ---------------- Kernel 4: gather + weighted sum + bias ----------------
__global__ __launch_bounds__(256) void k_gather(const float* __restrict__ xt,
                                                const float* __restrict__ v,
                                                const int* __restrict__ idx,
                                                const float* __restrict__ bias,
                                                float* __restrict__ out) {
    int t = threadIdx.x;
    int g = blockIdx.x * 2 + (t >> 7);
    int c = t & 127;
    if (g >= ROWS_TOTAL) return;
    int b = g / NN;
    int nb = b * NN;
    float acc = bias[c];
    int base = g * KK;
#pragma unroll
    for (int k = 0; k < KK; ++k) {
        int   ii = idx[base + k];
        float vv = v[base + k];
        acc += vv * xt[(size_t)(nb + ii) * CC + c];
    }
    out[(size_t)g * CC + c] = acc;
}

// ---------------- Kernel 5: GroupNorm stats per (b, group) ----------------
__global__ __launch_bounds__(256) void k_gnstats(const float* __restrict__ xin,
                                                 float* __restrict__ stats) {
    int bg = blockIdx.x; int b = bg >> 2; int gg = bg & 3;
    size_t base = (size_t)b * (NN * CC) + gg * CPG;
    float s1 = 0.f, s2 = 0.f;
    for (int i = threadIdx.x; i < NN * CPG; i += 256) {
        float x = xin[base + (size_t)(i >> 5) * CC + (i & 31)];
        s1 += x; s2 += x * x;
    }
#pragma unroll
    for (int off = 32; off > 0; off >>= 1) { s1 += __shfl_xor(s1, off); s2 += __shfl_xor(s2, off); }
    __shared__ float r1[4], r2[4];
    int w = threadIdx.x >> 6;
    if ((threadIdx.x & 63) == 0) { r1[w] = s1; r2[w] = s2; }
    __syncthreads();
    if (threadIdx.x == 0) {
        float a = r1[0] + r1[1] + r1[2] + r1[3];
        float qq = r2[0] + r2[1] + r2[2] + r2[3];
        const float inv = 1.0f / (float)(NN * CPG);
        float mean = a * inv;
        float var = qq * inv - mean * mean;
        stats[bg * 2]     = mean;
        stats[bg * 2 + 1] = rsqrtf(fmaxf(var, 0.f) + GN_EPS);
    }
}

// ---------------- Kernel 6: GN apply + SiLU (layout-preserving, fp32 out) ----------------
__global__ __launch_bounds__(256) void k_gnsilu(const float* __restrict__ xin,
                                                const float* __restrict__ stats,
                                                const float* __restrict__ gamma,
                                                const float* __restrict__ beta,
                                                float* __restrict__ out) {
    size_t e4 = ((size_t)blockIdx.x * 256 + threadIdx.x) * 4;
    int c0 = (int)(e4 & 127);
    int b  = (int)(e4 / (NN * CC));
    int gg = c0 >> 5;
    float mean = stats[(b * 4 + gg) * 2];
    float rstd = stats[(b * 4 + gg) * 2 + 1];
    float4 x = *(const float4*)&xin[e4];
    float g0 = gamma[c0], g1 = gamma[c0 + 1], g2 = gamma[c0 + 2], g3 = gamma[c0 + 3];
    float p0 = beta[c0],  p1 = beta[c0 + 1],  p2 = beta[c0 + 2],  p3 = beta[c0 + 3];
    float y0 = (x.x - mean) * rstd * g0 + p0;
    float y1 = (x.y - mean) * rstd * g1 + p1;
    float y2 = (x.z - mean) * rstd * g2 + p2;
    float y3 = (x.w - mean) * rstd * g3 + p3;
    float4 r;
    r.x = y0 / (1.0f + expf(-y0));
    r.y = y1 / (1.0f + expf(-y1));
    r.z = y2 / (1.0f + expf(-y2));
    r.w = y3 / (1.0f + expf(-y3));
    *(float4*)&out[e4] = r;
}

// ---------------- Kernel 7: GN apply + SiLU + transpose to [B][C][N], fp32 out ----------------
__global__ __launch_bounds__(256) void k_gnsilu_out(const float* __restrict__ xin,
                                                    const float* __restrict__ stats,
                                                    const float* __restrict__ gamma,
                                                    const float* __restrict__ beta,
                                                    float* __restrict__ out) {
    __shared__ float tile[32 * 65];
    int b = blockIdx.z, ct = blockIdx.y, nt = blockIdx.x;
    int c0 = ct * 32, n0 = nt * 64;
    int t = threadIdx.x;
    int cj = t & 31, ni0 = t >> 5;
    int gg = c0 >> 5;
    float mean = stats[(b * 4 + gg) * 2];
    float rstd = stats[(b * 4 + gg) * 2 + 1];
    float gm = gamma[c0 + cj];
    float bt = beta[c0 + cj];
#pragma unroll
    for (int i = 0; i < 8; ++i) {
        int n = n0 + ni0 + i * 8;
        if (n < NN) {
            float x = xin[((size_t)b * NN + n) * CC + c0 + cj];
            float y = (x - mean) * rstd * gm + bt;
            y = y / (1.0f + expf(-y));
            tile[cj * 65 + ni0 + i * 8] = y;
        }
    }
    __syncthreads();
    int nj = t & 63, ci0 = t >> 6;
#pragma unroll
    for (int i = 0; i < 8; ++i) {
        int c = ci0 + i * 4;
        int n = n0 + nj;
        if (n < NN) out[((size_t)b * CC + c0 + c) * NN + n] = tile[c * 65 + nj];
    }
}

extern "C" void kernel_launch(void* const* d_in, const int* in_sizes, int n_in,
                              void* d_out, int out_size, void* d_ws, size_t ws_size,
                              hipStream_t stream) {
    const float* x      = (const float*)d_in[0];
    const float* w1     = (const float*)d_in[1];
    const float* b1     = (const float*)d_in[2];
    const float* w2     = (const float*)d_in[3];
    const float* b2     = (const float*)d_in[4];
    const float* gamma1 = (const float*)d_in[5];
    const float* beta1  = (const float*)d_in[6];
    const float* gamma2 = (const float*)d_in[7];
    const float* beta2  = (const float*)d_in[8];
    float* out = (float*)d_out;

    const size_t BIG = (size_t)ROWS_TOTAL * CC;   // 8,294,400
    float* ws   = (float*)d_ws;
    float* bufB = ws;                              // gemm1out -> feat2 -> gath2
    f16*   xh   = (f16*)(ws + BIG);                // f16 split hi
    f16*   xl   = xh + BIG;                        // f16 split lo
    float* bufA = ws + BIG;                        // ALIASES xh/xl; first written by gather1
    float* vbuf = ws + 2 * BIG;                    // [64800*9]
    int*   ibuf = (int*)(ws + 2 * BIG + (size_t)ROWS_TOTAL * KK);
    float* stats = ws + 2 * BIG + 2 * (size_t)ROWS_TOTAL * KK;

    k_normalize<<<ROWS_TOTAL / 4, 256, 0, stream>>>(x, xh, xl);
    k_sim_topk<<<dim3(64, BN), 256, 0, stream>>>(xh, xl, vbuf, ibuf);

    // layer 1 (xh/xl last read by k_gemm_hl; bufA aliases them and is written after)
    k_gemm_hl<<<(ROWS_TOTAL + 31) / 32, 256, 0, stream>>>(xh, xl, w1, bufB);
    k_gather<<<ROWS_TOTAL / 2, 256, 0, stream>>>(bufB, vbuf, ibuf, b1, bufA);
    k_gnstats<<<BN * NGROUP, 256, 0, stream>>>(bufA, stats);
    k_gnsilu<<<(int)(BIG / 1024), 256, 0, stream>>>(bufA, stats, gamma1, beta1, bufB);

    // layer 2
    k_gemm<<<(ROWS_TOTAL + 31) / 32, 256, 0, stream>>>(bufB, w2, bufA);
    k_gather<<<ROWS_TOTAL / 2, 256, 0, stream>>>(bufA, vbuf, ibuf, b2, bufB);
    k_gnstats<<<BN * NGROUP, 256, 0, stream>>>(bufB, stats);
    k_gnsilu_out<<<dim3((NN + 63) / 64, NGROUP, BN), 256, 0, stream>>>(bufB, stats, gamma2, beta2, out);
}

// Round 7
// 919.982 us; speedup vs baseline: 1.1610x; 1.1558x over previous
//
#include <hip/hip_runtime.h>
#include <hip/hip_bf16.h>

#define BN 32
#define CC 128
#define NN 2025
#define KK 9
#define NGROUP 4
#define CPG 32
#define GN_EPS 1e-5f
#define ROWS_TOTAL (BN * NN)   // 64800

typedef _Float16 f16;
typedef __attribute__((ext_vector_type(8))) _Float16 f16x8;
typedef __attribute__((ext_vector_type(4))) float f32x4;

#define S28 3.725290298461914e-09f   // 2^-28
#define S40 9.094947017729282e-13f   // 2^-40
#define RH  6.103515625e-05f         // 2^-14
#define RL  1.4901161193847656e-08f  // 2^-26

#define T0F 0.17f                    // survivor threshold (9th-best ~0.23, min ~0.19)
#define CAP 100                      // per-row survivor capacity (mean ~55, max ~95; overflow -> exact fallback)

// ---------------- Kernel 1: L2 normalize -> scaled f16 split, row-major [B*N][C] ----------------
__global__ __launch_bounds__(256) void k_normalize(const float* __restrict__ x,
                                                   f16* __restrict__ xh, f16* __restrict__ xl) {
    int wid  = blockIdx.x * 4 + (threadIdx.x >> 6);   // one wave per (b,n)
    int lane = threadIdx.x & 63;
    int b = wid / NN;
    int n = wid - b * NN;
    float v0 = x[(b * CC + lane) * NN + n];
    float v1 = x[(b * CC + lane + 64) * NN + n];
    float ss = v0 * v0 + v1 * v1;
#pragma unroll
    for (int off = 32; off > 0; off >>= 1) ss += __shfl_xor(ss, off);
    float s = 1.0f / fmaxf(sqrtf(ss), 1e-12f);
    v0 *= s; v1 *= s;
    float w0 = v0 * 16384.0f, w1 = v1 * 16384.0f;
    f16 h0 = (f16)w0, h1 = (f16)w1;
    f16 l0 = (f16)((w0 - (float)h0) * 4096.0f);
    f16 l1 = (f16)((w1 - (float)h1) * 4096.0f);
    size_t base = (size_t)wid * CC;
    xh[base + lane] = h0;  xh[base + lane + 64] = h1;
    xl[base + lane] = l0;  xl[base + lane + 64] = l1;
}

// top-9 insert: (value desc, index asc) ordering; order-independent tie rules
__device__ __forceinline__ void ins9(float cand, int m, float* v, int* ix,
                                     float& mv, int& mi, int& mp) {
    bool take = (cand > mv) || ((cand == mv) && (m < mi));
    if (take) {
#pragma unroll
        for (int k = 0; k < 9; ++k) if (k == mp) { v[k] = cand; ix[k] = m; }
        float nv = v[0]; int ni = ix[0]; int np = 0;
#pragma unroll
        for (int k = 1; k < 9; ++k) {
            if (v[k] < nv || (v[k] == nv && ix[k] > ni)) { nv = v[k]; ni = ix[k]; np = k; }
        }
        mv = nv; mi = ni; mp = np;
    }
}

// ---------------- Kernel 2: fused sim + top-k: MFMA + threshold compaction ----------------
// R7: bandwidth restructure. R0/R2/R6 established dur ∝ A-bytes at ~26 GB/s/CU
// (scattered 16-row x 64B segments on the L1-miss path), independent of occupancy
// (16 vs 27 waves/CU) and of data residence (L3 in R2, L2 in R4/R6). Fix BOTH terms:
//   - 64 sim-rows/block (1024 blocks): blocks-per-batch 64->32 => unique A-bytes
//     halve to 1.06GB.
//   - each wave owns ONE 16-row B-tile (32 B-regs, under the 64-VGPR cliff); ALL 4
//     waves sweep the SAME 16-m A-window per chunk in barrier-lockstep => identical
//     addresses merge in L1/MSHR => per-CU L1-miss traffic /4.
//   - survivors now 64 rows: LDS 39.4KB => 4 blocks/CU => grid 1024 = one exact round.
//   - XCD swizzle kept: id&7 -> XCD -> batch b%8 (batches 4/XCD, A-slices L2-resident).
// Accumulation order & selection machinery unchanged => results identical to R2/R4.
// Tripwires: VGPR <= ~70 & WRITE_SIZE ~4.6MB (else spill); dur > 250us => L1 merge
// failed, next step explicit LDS staging.
__global__ __launch_bounds__(256) void k_sim_topk(const f16* __restrict__ xh, const f16* __restrict__ xl,
                                                  float* __restrict__ vout, int* __restrict__ iout) {
    __shared__ float          sv[64][CAP + 1];   // stride 101 dw; gcd(101%32=5,32)=1: conflict-free
    __shared__ unsigned short si[64][CAP + 2];   // stride 204B=51 dw; gcd(51%32=19,32)=1: conflict-free
    __shared__ int   cnt[64];
    __shared__ int   nbad;
    __shared__ int   badrows[64];

    // Swizzle (bijective over 1024): id&7 -> XCD slot -> batch b%8; (id>>3)&31 -> r-block
    // within batch; id>>8 -> batch quad. 32 blocks x 64 rows cover NN=2025 (clamped).
    const int id   = blockIdx.x;                  // 0..1023
    const int b    = (id & 7) + 8 * (id >> 8);
    const int r0   = ((id >> 3) & 31) * 64;
    const int t    = threadIdx.x;
    const int w    = t >> 6;
    const int lane = t & 63;
    const int jr   = lane & 15;
    const int q    = lane >> 4;

    if (t < 64) cnt[t] = 0;
    if (t == 0) nbad = 0;

    // B fragments: wave w owns sim-rows [r0+16w, r0+16w+16); lane k-window = s*32 + q*8
    f16x8 bh[4], bl[4];
    {
        int rr = b * NN + min(r0 + w * 16 + jr, NN - 1);
        const f16* pH = xh + (size_t)rr * CC;
        const f16* pL = xl + (size_t)rr * CC;
#pragma unroll
        for (int s = 0; s < 4; ++s) {
            bh[s] = *(const f16x8*)(pH + s * 32 + q * 8);
            bl[s] = *(const f16x8*)(pL + s * 32 + q * 8);
        }
    }
    __syncthreads();

    // Main loop: 127 chunks of 16 m; ALL waves read the SAME A-window (L1 broadcast).
    // Bucket rbuf is wave-private (w*16+jr) => no inter-wave races on cnt/sv/si.
    const int rbuf = w * 16 + jr;
    for (int chunk = 0; chunk < 127; ++chunk) {
        const int mb = chunk * 16;
        const int marow = b * NN + min(mb + jr, NN - 1);    // A row = m-side (same for all waves)
        const f16* aHp = xh + (size_t)marow * CC;
        const f16* aLp = xl + (size_t)marow * CC;
        f32x4 h0 = {0.f, 0.f, 0.f, 0.f}, l0 = {0.f, 0.f, 0.f, 0.f};
#pragma unroll
        for (int s = 0; s < 4; ++s) {
            f16x8 ah = *(const f16x8*)(aHp + s * 32 + q * 8);
            f16x8 al = *(const f16x8*)(aLp + s * 32 + q * 8);
            h0 = __builtin_amdgcn_mfma_f32_16x16x32_f16(ah, bh[s], h0, 0, 0, 0);
            l0 = __builtin_amdgcn_mfma_f32_16x16x32_f16(ah, bl[s], l0, 0, 0, 0);
            l0 = __builtin_amdgcn_mfma_f32_16x16x32_f16(al, bh[s], l0, 0, 0, 0);
        }
        // threshold compaction: candidate (row = rbuf, m = mb + q*4 + reg)
#pragma unroll
        for (int reg = 0; reg < 4; ++reg) {
            int m = mb + q * 4 + reg;
            float c0 = h0[reg] * S28 + l0[reg] * S40;
            if (m < NN && c0 > T0F) {
                int pos = atomicAdd(&cnt[rbuf], 1);
                if (pos < CAP) { sv[rbuf][pos] = c0; si[rbuf][pos] = (unsigned short)m; }
            }
        }
        __syncthreads();   // lockstep the 4 waves so their identical A-loads merge in L1
    }
    __syncthreads();

    // Pass B: exact top-9 over survivors, one thread per row (64 rows)
    if (t < 64) {
        int r = r0 + t;
        if (r < NN) {
            int c = cnt[t];
            if (c >= 9 && c <= CAP) {
                float fv[9]; int fi[9];
#pragma unroll
                for (int k = 0; k < 9; ++k) { fv[k] = -3.0e38f; fi[k] = 0x7fffffff; }
                float mv = -3.0e38f; int mi = 0x7fffffff; int mp = 0;
                for (int j = 0; j < c; ++j) ins9(sv[t][j], (int)si[t][j], fv, fi, mv, mi, mp);
                float s = 1e-6f;
#pragma unroll
                for (int k = 0; k < 9; ++k) s += fv[k];
                float inv = 1.0f / s;
                int base = (b * NN + r) * KK;
#pragma unroll
                for (int k = 0; k < 9; ++k) { vout[base + k] = fv[k] * inv; iout[base + k] = fi[k]; }
            } else {
                int slot = atomicAdd(&nbad, 1);
                badrows[slot] = r;
            }
        }
    }
    __syncthreads();

    // Fallback: wave 0 exactly re-solves any bad rows (expected: none)
    if (w == 0) {
        int nb = nbad;
        for (int ib = 0; ib < nb; ++ib) {
            int r = badrows[ib];
            const f16* rH = xh + ((size_t)b * NN + r) * CC;
            const f16* rL = xl + ((size_t)b * NN + r) * CC;
            float fv[9]; int fi[9];
#pragma unroll
            for (int k = 0; k < 9; ++k) { fv[k] = -3.0e38f; fi[k] = 0x7fffffff; }
            float mv = -3.0e38f; int mi = 0x7fffffff; int mp = 0;
            for (int m = lane; m < NN; m += 64) {
                const f16* mH = xh + ((size_t)b * NN + m) * CC;
                const f16* mL = xl + ((size_t)b * NN + m) * CC;
                float a1 = 0.f, a2 = 0.f;
                for (int c2 = 0; c2 < CC; ++c2) {
                    float hr = (float)rH[c2], hm = (float)mH[c2];
                    float lr = (float)rL[c2], lm = (float)mL[c2];
                    a1 += hr * hm;
                    a2 += hr * lm + lr * hm;
                }
                ins9(a1 * S28 + a2 * S40, m, fv, fi, mv, mi, mp);
            }
#pragma unroll
            for (int off = 1; off < 64; off <<= 1) {
                float pv[9]; int pi[9];
#pragma unroll
                for (int k = 0; k < 9; ++k) { pv[k] = __shfl_xor(fv[k], off); pi[k] = __shfl_xor(fi[k], off); }
#pragma unroll
                for (int k = 0; k < 9; ++k) ins9(pv[k], pi[k], fv, fi, mv, mi, mp);
            }
            if (lane == 0) {
                float s = 1e-6f;
#pragma unroll
                for (int k = 0; k < 9; ++k) s += fv[k];
                float inv = 1.0f / s;
                int base = (b * NN + r) * KK;
#pragma unroll
                for (int k = 0; k < 9; ++k) { vout[base + k] = fv[k] * inv; iout[base + k] = fi[k]; }
            }
        }
    }
}

// ---------------- Kernel 3a: GEMM out = reconstruct(xh,xl) @ w  (layer 1) ----------------
#define RST 36
__global__ __launch_bounds__(256) void k_gemm_hl(const f16* __restrict__ xh, const f16* __restrict__ xl,
                                                 const float* __restrict__ w, float* __restrict__ out) {
    __shared__ float rowsT[CC * RST];
    int t = threadIdx.x;
    int row0 = blockIdx.x * 32;
    for (int it = 0; it < 16; ++it) {
        int qq = t + it * 256;
        int c = qq & 127, r = qq >> 7;
        size_t idx = (size_t)(row0 + r) * CC + c;
        rowsT[c * RST + r] = (float)xh[idx] * RH + (float)xl[idx] * RL;
    }
    __syncthreads();
    int j = t & 127, half = t >> 7;
    float acc[16];
#pragma unroll
    for (int r = 0; r < 16; ++r) acc[r] = 0.0f;
    for (int c = 0; c < CC; ++c) {
        float wv = w[c * CC + j];
        const float4* ap = (const float4*)&rowsT[c * RST + half * 16];
        float4 a0 = ap[0], a1 = ap[1], a2 = ap[2], a3 = ap[3];
        acc[0]  += a0.x * wv; acc[1]  += a0.y * wv; acc[2]  += a0.z * wv; acc[3]  += a0.w * wv;
        acc[4]  += a1.x * wv; acc[5]  += a1.y * wv; acc[6]  += a1.z * wv; acc[7]  += a1.w * wv;
        acc[8]  += a2.x * wv; acc[9]  += a2.y * wv; acc[10] += a2.z * wv; acc[11] += a2.w * wv;
        acc[12] += a3.x * wv; acc[13] += a3.y * wv; acc[14] += a3.z * wv; acc[15] += a3.w * wv;
    }
#pragma unroll
    for (int r = 0; r < 16; ++r) out[(size_t)(row0 + half * 16 + r) * CC + j] = acc[r];
}

// ---------------- Kernel 3b: GEMM fp32 in (layer 2) ----------------
__global__ __launch_bounds__(256) void k_gemm(const float* __restrict__ in,
                                              const float* __restrict__ w,
                                              float* __restrict__ out) {
    __shared__ float rowsT[CC * RST];
    int t = threadIdx.x;
    int row0 = blockIdx.x * 32;
    for (int it = 0; it < 16; ++it) {
        int qq = t + it * 256;
        int c = qq & 127, r = qq >> 7;
        rowsT[c * RST + r] = in[(size_t)(row0 + r) * CC + c];
    }
    __syncthreads();
    int j = t & 127, half = t >> 7;
    float acc[16];
#pragma unroll
    for (int r = 0; r < 16; ++r) acc[r] = 0.0f;
    for (int c = 0; c < CC; ++c) {
        float wv = w[c * CC + j];
        const float4* ap = (const float4*)&rowsT[c * RST + half * 16];
        float4 a0 = ap[0], a1 = ap[1], a2 = ap[2], a3 = ap[3];
        acc[0]  += a0.x * wv; acc[1]  += a0.y * wv; acc[2]  += a0.z * wv; acc[3]  += a0.w * wv;
        acc[4]  += a1.x * wv; acc[5]  += a1.y * wv; acc[6]  += a1.z * wv; acc[7]  += a1.w * wv;
        acc[8]  += a2.x * wv; acc[9]  += a2.y * wv; acc[10] += a2.z * wv; acc[11] += a2.w * wv;
        acc[12] += a3.x * wv; acc[13] += a3.y * wv; acc[14] += a3.z * wv; acc[15] += a3.w * wv;
    }
#pragma unroll
    for (int r = 0; r < 16; ++r) out[(size_t)(row0 + half * 16 + r) * CC + j] = acc[r];
}

// ---------------- Kernel 4: gather + weighted sum + bias ----------------
__global__ __launch_bounds__(256) void k_gather(const float* __restrict__ xt,
                                                const float* __restrict__ v,
                                                const int* __restrict__ idx,
                                                const float* __restrict__ bias,
                                                float* __restrict__ out) {
    int t = threadIdx.x;
    int g = blockIdx.x * 2 + (t >> 7);
    int c = t & 127;
    if (g >= ROWS_TOTAL) return;
    int b = g / NN;
    int nb = b * NN;
    float acc = bias[c];
    int base = g * KK;
#pragma unroll
    for (int k = 0; k < KK; ++k) {
        int   ii = idx[base + k];
        float vv = v[base + k];
        acc += vv * xt[(size_t)(nb + ii) * CC + c];
    }
    out[(size_t)g * CC + c] = acc;
}

// ---------------- Kernel 5: GroupNorm stats per (b, group) ----------------
__global__ __launch_bounds__(256) void k_gnstats(const float* __restrict__ xin,
                                                 float* __restrict__ stats) {
    int bg = blockIdx.x; int b = bg >> 2; int gg = bg & 3;
    size_t base = (size_t)b * (NN * CC) + gg * CPG;
    float s1 = 0.f, s2 = 0.f;
    for (int i = threadIdx.x; i < NN * CPG; i += 256) {
        float x = xin[base + (size_t)(i >> 5) * CC + (i & 31)];
        s1 += x; s2 += x * x;
    }
#pragma unroll
    for (int off = 32; off > 0; off >>= 1) { s1 += __shfl_xor(s1, off); s2 += __shfl_xor(s2, off); }
    __shared__ float r1[4], r2[4];
    int w = threadIdx.x >> 6;
    if ((threadIdx.x & 63) == 0) { r1[w] = s1; r2[w] = s2; }
    __syncthreads();
    if (threadIdx.x == 0) {
        float a = r1[0] + r1[1] + r1[2] + r1[3];
        float qq = r2[0] + r2[1] + r2[2] + r2[3];
        const float inv = 1.0f / (float)(NN * CPG);
        float mean = a * inv;
        float var = qq * inv - mean * mean;
        stats[bg * 2]     = mean;
        stats[bg * 2 + 1] = rsqrtf(fmaxf(var, 0.f) + GN_EPS);
    }
}

// ---------------- Kernel 6: GN apply + SiLU (layout-preserving, fp32 out) ----------------
__global__ __launch_bounds__(256) void k_gnsilu(const float* __restrict__ xin,
                                                const float* __restrict__ stats,
                                                const float* __restrict__ gamma,
                                                const float* __restrict__ beta,
                                                float* __restrict__ out) {
    size_t e4 = ((size_t)blockIdx.x * 256 + threadIdx.x) * 4;
    int c0 = (int)(e4 & 127);
    int b  = (int)(e4 / (NN * CC));
    int gg = c0 >> 5;
    float mean = stats[(b * 4 + gg) * 2];
    float rstd = stats[(b * 4 + gg) * 2 + 1];
    float4 x = *(const float4*)&xin[e4];
    float g0 = gamma[c0], g1 = gamma[c0 + 1], g2 = gamma[c0 + 2], g3 = gamma[c0 + 3];
    float p0 = beta[c0],  p1 = beta[c0 + 1],  p2 = beta[c0 + 2],  p3 = beta[c0 + 3];
    float y0 = (x.x - mean) * rstd * g0 + p0;
    float y1 = (x.y - mean) * rstd * g1 + p1;
    float y2 = (x.z - mean) * rstd * g2 + p2;
    float y3 = (x.w - mean) * rstd * g3 + p3;
    float4 r;
    r.x = y0 / (1.0f + expf(-y0));
    r.y = y1 / (1.0f + expf(-y1));
    r.z = y2 / (1.0f + expf(-y2));
    r.w = y3 / (1.0f + expf(-y3));
    *(float4*)&out[e4] = r;
}

// ---------------- Kernel 7: GN apply + SiLU + transpose to [B][C][N], fp32 out ----------------
__global__ __launch_bounds__(256) void k_gnsilu_out(const float* __restrict__ xin,
                                                    const float* __restrict__ stats,
                                                    const float* __restrict__ gamma,
                                                    const float* __restrict__ beta,
                                                    float* __restrict__ out) {
    __shared__ float tile[32 * 65];
    int b = blockIdx.z, ct = blockIdx.y, nt = blockIdx.x;
    int c0 = ct * 32, n0 = nt * 64;
    int t = threadIdx.x;
    int cj = t & 31, ni0 = t >> 5;
    int gg = c0 >> 5;
    float mean = stats[(b * 4 + gg) * 2];
    float rstd = stats[(b * 4 + gg) * 2 + 1];
    float gm = gamma[c0 + cj];
    float bt = beta[c0 + cj];
#pragma unroll
    for (int i = 0; i < 8; ++i) {
        int n = n0 + ni0 + i * 8;
        if (n < NN) {
            float x = xin[((size_t)b * NN + n) * CC + c0 + cj];
            float y = (x - mean) * rstd * gm + bt;
            y = y / (1.0f + expf(-y));
            tile[cj * 65 + ni0 + i * 8] = y;
        }
    }
    __syncthreads();
    int nj = t & 63, ci0 = t >> 6;
#pragma unroll
    for (int i = 0; i < 8; ++i) {
        int c = ci0 + i * 4;
        int n = n0 + nj;
        if (n < NN) out[((size_t)b * CC + c0 + c) * NN + n] = tile[c * 65 + nj];
    }
}

extern "C" void kernel_launch(void* const* d_in, const int* in_sizes, int n_in,
                              void* d_out, int out_size, void* d_ws, size_t ws_size,
                              hipStream_t stream) {
    const float* x      = (const float*)d_in[0];
    const float* w1     = (const float*)d_in[1];
    const float* b1     = (const float*)d_in[2];
    const float* w2     = (const float*)d_in[3];
    const float* b2     = (const float*)d_in[4];
    const float* gamma1 = (const float*)d_in[5];
    const float* beta1  = (const float*)d_in[6];
    const float* gamma2 = (const float*)d_in[7];
    const float* beta2  = (const float*)d_in[8];
    float* out = (float*)d_out;

    const size_t BIG = (size_t)ROWS_TOTAL * CC;   // 8,294,400
    float* ws   = (float*)d_ws;
    float* bufB = ws;                              // gemm1out -> feat2 -> gath2
    f16*   xh   = (f16*)(ws + BIG);                // f16 split hi
    f16*   xl   = xh + BIG;                        // f16 split lo
    float* bufA = ws + BIG;                        // ALIASES xh/xl; first written by gather1
    float* vbuf = ws + 2 * BIG;                    // [64800*9]
    int*   ibuf = (int*)(ws + 2 * BIG + (size_t)ROWS_TOTAL * KK);
    float* stats = ws + 2 * BIG + 2 * (size_t)ROWS_TOTAL * KK;

    k_normalize<<<ROWS_TOTAL / 4, 256, 0, stream>>>(x, xh, xl);
    k_sim_topk<<<1024, 256, 0, stream>>>(xh, xl, vbuf, ibuf);

    // layer 1 (xh/xl last read by k_gemm_hl; bufA aliases them and is written after)
    k_gemm_hl<<<(ROWS_TOTAL + 31) / 32, 256, 0, stream>>>(xh, xl, w1, bufB);
    k_gather<<<ROWS_TOTAL / 2, 256, 0, stream>>>(bufB, vbuf, ibuf, b1, bufA);
    k_gnstats<<<BN * NGROUP, 256, 0, stream>>>(bufA, stats);
    k_gnsilu<<<(int)(BIG / 1024), 256, 0, stream>>>(bufA, stats, gamma1, beta1, bufB);

    // layer 2
    k_gemm<<<(ROWS_TOTAL + 31) / 32, 256, 0, stream>>>(bufB, w2, bufA);
    k_gather<<<ROWS_TOTAL / 2, 256, 0, stream>>>(bufA, vbuf, ibuf, b2, bufB);
    k_gnstats<<<BN * NGROUP, 256, 0, stream>>>(bufB, stats);
    k_gnsilu_out<<<dim3((NN + 63) / 64, NGROUP, BN), 256, 0, stream>>>(bufB, stats, gamma2, beta2, out);
}

// Round 9
// 683.114 us; speedup vs baseline: 1.5635x; 1.3467x over previous
//
#include <hip/hip_runtime.h>
#include <hip/hip_bf16.h>

#define BN 32
#define CC 128
#define NN 2025
#define KK 9
#define NGROUP 4
#define CPG 32
#define GN_EPS 1e-5f
#define ROWS_TOTAL (BN * NN)   // 64800

typedef _Float16 f16;
typedef __attribute__((ext_vector_type(8))) _Float16 f16x8;
typedef __attribute__((ext_vector_type(4))) float f32x4;

#define S28 3.725290298461914e-09f   // 2^-28
#define S40 9.094947017729282e-13f   // 2^-40
#define RH  6.103515625e-05f         // 2^-14
#define RL  1.4901161193847656e-08f  // 2^-26

#define T0F 0.17f                    // survivor threshold (9th-best ~0.23, min ~0.19)
#define CAP 100                      // per-row survivor capacity (mean ~55, max ~95; overflow -> exact fallback)

// ---------------- Kernel 1: L2 normalize -> scaled f16 split, row-major [B*N][C] ----------------
__global__ __launch_bounds__(256) void k_normalize(const float* __restrict__ x,
                                                   f16* __restrict__ xh, f16* __restrict__ xl) {
    int wid  = blockIdx.x * 4 + (threadIdx.x >> 6);   // one wave per (b,n)
    int lane = threadIdx.x & 63;
    int b = wid / NN;
    int n = wid - b * NN;
    float v0 = x[(b * CC + lane) * NN + n];
    float v1 = x[(b * CC + lane + 64) * NN + n];
    float ss = v0 * v0 + v1 * v1;
#pragma unroll
    for (int off = 32; off > 0; off >>= 1) ss += __shfl_xor(ss, off);
    float s = 1.0f / fmaxf(sqrtf(ss), 1e-12f);
    v0 *= s; v1 *= s;
    float w0 = v0 * 16384.0f, w1 = v1 * 16384.0f;
    f16 h0 = (f16)w0, h1 = (f16)w1;
    f16 l0 = (f16)((w0 - (float)h0) * 4096.0f);
    f16 l1 = (f16)((w1 - (float)h1) * 4096.0f);
    size_t base = (size_t)wid * CC;
    xh[base + lane] = h0;  xh[base + lane + 64] = h1;
    xl[base + lane] = l0;  xl[base + lane + 64] = l1;
}

// top-9 insert: (value desc, index asc) ordering; order-independent tie rules — EXACT
__device__ __forceinline__ void ins9(float cand, int m, float* v, int* ix,
                                     float& mv, int& mi, int& mp) {
    bool take = (cand > mv) || ((cand == mv) && (m < mi));
    if (take) {
#pragma unroll
        for (int k = 0; k < 9; ++k) if (k == mp) { v[k] = cand; ix[k] = m; }
        float nv = v[0]; int ni = ix[0]; int np = 0;
#pragma unroll
        for (int k = 1; k < 9; ++k) {
            if (v[k] < nv || (v[k] == nv && ix[k] > ni)) { nv = v[k]; ni = ix[k]; np = k; }
        }
        mv = nv; mi = ni; mp = np;
    }
}

// ---------------- Kernel 2: fused sim + top-k: LDS-staged MFMA + threshold compaction ----------------
// R9. R8's FAILURE (absmax 0.43) was the lossy 21-bit survivor pack: truncation error
// ~6e-5 flips top-9 SELECTION whenever the rank-9/10 gap < 1.2e-4 (common among 2025
// candidates) — discrete large error, unlike value perturbation. Reverted to EXACT
// float sv + u16 si survivors (R7's pass B verbatim).
// Kept from R8: coalesced global->LDS staging (R7 proved dur tracks scattered L1-miss
// transactions at ~26 GB/s/CU; implicit 4-wave L1 merge only bought 1.32x).
// Shape: 32 sim-rows/block, 2048 blocks (2 even rounds @ 4 blocks/CU). Wave w =
// (tile tw=w&1, m-half mh=w>>1); one staged 32-m window shared per chunk, 64 chunks.
// Staging layout stg[hl][row][frag ^ (row&7)]: both write (ri,fi) and read (q,jr)
// patterns land exactly 8 lanes per 4-bank class with distinct addresses = the wave64
// b128 throughput floor (no excess conflicts on either side).
// Tripwires: WRITE_SIZE ~4.6MB (spill); bank-conflict >>1e6 => bank model wrong;
// absmax must return to 0.0078.
__global__ __launch_bounds__(256) void k_sim_topk(const f16* __restrict__ xh, const f16* __restrict__ xl,
                                                  float* __restrict__ vout, int* __restrict__ iout) {
    __shared__ f16x8          stg[2][32][16];  // 16KB staged 32-m window: [hl][row][frag^(row&7)]
    __shared__ float          sv[32][CAP + 1]; // stride 101 dw; gcd(101%32=5,32)=1: conflict-free
    __shared__ unsigned short si[32][CAP + 2]; // stride 204B=51 dw; gcd(51%32=19,32)=1: conflict-free
    __shared__ int   cnt[32];
    __shared__ int   nbad;
    __shared__ int   badrows[32];

    // XCD batch-affinity swizzle (bijective over 2048): id&7 -> XCD slot -> batch b%8;
    // consecutive ids on one XCD walk r0 within the SAME batch (A-slice L2-resident).
    const int id   = blockIdx.x;                  // 0..2047
    const int b    = (id & 7) + 8 * (id >> 9);
    const int r0   = ((id >> 3) & 63) * 32;
    const int t    = threadIdx.x;
    const int w    = t >> 6;
    const int lane = t & 63;
    const int jr   = lane & 15;
    const int q    = lane >> 4;
    const int tw   = w & 1;          // which 16-row B-tile this wave owns
    const int mh   = w >> 1;         // which 16-m half of the staged window

    if (t < 32) cnt[t] = 0;
    if (t == 0) nbad = 0;

    // B fragments: wave's tile rows r0 + tw*16 + jr; lane k-window = s*32 + q*8
    f16x8 bh[4], bl[4];
    {
        int rr = b * NN + min(r0 + tw * 16 + jr, NN - 1);
        const f16* pH = xh + (size_t)rr * CC;
        const f16* pL = xl + (size_t)rr * CC;
#pragma unroll
        for (int s = 0; s < 4; ++s) {
            bh[s] = *(const f16x8*)(pH + s * 32 + q * 8);
            bl[s] = *(const f16x8*)(pL + s * 32 + q * 8);
        }
    }

    // Staging roles: thread t loads frag fi_ of window rows ri_ and ri_+16, both hl.
    const int fi_ = t & 15;
    const int ri_ = t >> 4;                 // 0..15
    const int fx  = fi_ ^ (ri_ & 7);        // swizzled frag slot ((ri_+16)&7 == ri_&7)
    const int rbuf = tw * 16 + jr;          // survivor bucket = block-local sim-row

    // preload chunk 0
    f16x8 h0r, h1r, l0r, l1r;
    {
        size_t g0 = (size_t)(b * NN + min(ri_, NN - 1)) * CC + fi_ * 8;
        size_t g1 = (size_t)(b * NN + min(ri_ + 16, NN - 1)) * CC + fi_ * 8;
        h0r = *(const f16x8*)(xh + g0);  h1r = *(const f16x8*)(xh + g1);
        l0r = *(const f16x8*)(xl + g0);  l1r = *(const f16x8*)(xl + g1);
    }

    for (int chunk = 0; chunk < 64; ++chunk) {
        __syncthreads();                     // all waves done reading previous window
        stg[0][ri_][fx]      = h0r;
        stg[0][ri_ + 16][fx] = h1r;
        stg[1][ri_][fx]      = l0r;
        stg[1][ri_ + 16][fx] = l1r;
        __syncthreads();                     // window visible
        if (chunk < 63) {                    // issue next window's loads under compute
            size_t g0 = (size_t)(b * NN + min((chunk + 1) * 32 + ri_, NN - 1)) * CC + fi_ * 8;
            size_t g1 = (size_t)(b * NN + min((chunk + 1) * 32 + ri_ + 16, NN - 1)) * CC + fi_ * 8;
            h0r = *(const f16x8*)(xh + g0);  h1r = *(const f16x8*)(xh + g1);
            l0r = *(const f16x8*)(xl + g0);  l1r = *(const f16x8*)(xl + g1);
        }
        __builtin_amdgcn_sched_barrier(0);   // keep loads issued before the MFMA cluster

        const int mb   = chunk * 32 + mh * 16;
        const int arow = mh * 16 + jr;       // lane's A row within the staged window
        const int axr  = arow & 7;
        f32x4 hh = {0.f, 0.f, 0.f, 0.f}, ll = {0.f, 0.f, 0.f, 0.f};
#pragma unroll
        for (int s = 0; s < 4; ++s) {
            f16x8 ah = stg[0][arow][(s * 4 + q) ^ axr];
            f16x8 al = stg[1][arow][(s * 4 + q) ^ axr];
            hh = __builtin_amdgcn_mfma_f32_16x16x32_f16(ah, bh[s], hh, 0, 0, 0);
            ll = __builtin_amdgcn_mfma_f32_16x16x32_f16(ah, bl[s], ll, 0, 0, 0);
            ll = __builtin_amdgcn_mfma_f32_16x16x32_f16(al, bh[s], ll, 0, 0, 0);
        }
        // threshold compaction: candidate (sim-row rbuf, m = mb + q*4 + reg) — EXACT store
#pragma unroll
        for (int reg = 0; reg < 4; ++reg) {
            int m = mb + q * 4 + reg;
            float c0 = hh[reg] * S28 + ll[reg] * S40;
            if (m < NN && c0 > T0F) {
                int pos = atomicAdd(&cnt[rbuf], 1);
                if (pos < CAP) { sv[rbuf][pos] = c0; si[rbuf][pos] = (unsigned short)m; }
            }
        }
    }
    __syncthreads();

    // Pass B: exact top-9 over survivors, one thread per row (32 rows)
    if (t < 32) {
        int r = r0 + t;
        if (r < NN) {
            int c = cnt[t];
            if (c >= 9 && c <= CAP) {
                float fv[9]; int fi[9];
#pragma unroll
                for (int k = 0; k < 9; ++k) { fv[k] = -3.0e38f; fi[k] = 0x7fffffff; }
                float mv = -3.0e38f; int mi = 0x7fffffff; int mp = 0;
                for (int j = 0; j < c; ++j) ins9(sv[t][j], (int)si[t][j], fv, fi, mv, mi, mp);
                float s = 1e-6f;
#pragma unroll
                for (int k = 0; k < 9; ++k) s += fv[k];
                float inv = 1.0f / s;
                int base = (b * NN + r) * KK;
#pragma unroll
                for (int k = 0; k < 9; ++k) { vout[base + k] = fv[k] * inv; iout[base + k] = fi[k]; }
            } else {
                int slot = atomicAdd(&nbad, 1);
                badrows[slot] = r;
            }
        }
    }
    __syncthreads();

    // Fallback: wave 0 exactly re-solves any bad rows (expected: none)
    if (w == 0) {
        int nb = nbad;
        for (int ib = 0; ib < nb; ++ib) {
            int r = badrows[ib];
            const f16* rH = xh + ((size_t)b * NN + r) * CC;
            const f16* rL = xl + ((size_t)b * NN + r) * CC;
            float fv[9]; int fi[9];
#pragma unroll
            for (int k = 0; k < 9; ++k) { fv[k] = -3.0e38f; fi[k] = 0x7fffffff; }
            float mv = -3.0e38f; int mi = 0x7fffffff; int mp = 0;
            for (int m = lane; m < NN; m += 64) {
                const f16* mH = xh + ((size_t)b * NN + m) * CC;
                const f16* mL = xl + ((size_t)b * NN + m) * CC;
                float a1 = 0.f, a2 = 0.f;
                for (int c2 = 0; c2 < CC; ++c2) {
                    float hr = (float)rH[c2], hm = (float)mH[c2];
                    float lr = (float)rL[c2], lm = (float)mL[c2];
                    a1 += hr * hm;
                    a2 += hr * lm + lr * hm;
                }
                ins9(a1 * S28 + a2 * S40, m, fv, fi, mv, mi, mp);
            }
#pragma unroll
            for (int off = 1; off < 64; off <<= 1) {
                float pv[9]; int pi[9];
#pragma unroll
                for (int k = 0; k < 9; ++k) { pv[k] = __shfl_xor(fv[k], off); pi[k] = __shfl_xor(fi[k], off); }
#pragma unroll
                for (int k = 0; k < 9; ++k) ins9(pv[k], pi[k], fv, fi, mv, mi, mp);
            }
            if (lane == 0) {
                float s = 1e-6f;
#pragma unroll
                for (int k = 0; k < 9; ++k) s += fv[k];
                float inv = 1.0f / s;
                int base = (b * NN + r) * KK;
#pragma unroll
                for (int k = 0; k < 9; ++k) { vout[base + k] = fv[k] * inv; iout[base + k] = fi[k]; }
            }
        }
    }
}

// ---------------- Kernel 3a: GEMM out = reconstruct(xh,xl) @ w  (layer 1) ----------------
#define RST 36
__global__ __launch_bounds__(256) void k_gemm_hl(const f16* __restrict__ xh, const f16* __restrict__ xl,
                                                 const float* __restrict__ w, float* __restrict__ out) {
    __shared__ float rowsT[CC * RST];
    int t = threadIdx.x;
    int row0 = blockIdx.x * 32;
    for (int it = 0; it < 16; ++it) {
        int qq = t + it * 256;
        int c = qq & 127, r = qq >> 7;
        size_t idx = (size_t)(row0 + r) * CC + c;
        rowsT[c * RST + r] = (float)xh[idx] * RH + (float)xl[idx] * RL;
    }
    __syncthreads();
    int j = t & 127, half = t >> 7;
    float acc[16];
#pragma unroll
    for (int r = 0; r < 16; ++r) acc[r] = 0.0f;
    for (int c = 0; c < CC; ++c) {
        float wv = w[c * CC + j];
        const float4* ap = (const float4*)&rowsT[c * RST + half * 16];
        float4 a0 = ap[0], a1 = ap[1], a2 = ap[2], a3 = ap[3];
        acc[0]  += a0.x * wv; acc[1]  += a0.y * wv; acc[2]  += a0.z * wv; acc[3]  += a0.w * wv;
        acc[4]  += a1.x * wv; acc[5]  += a1.y * wv; acc[6]  += a1.z * wv; acc[7]  += a1.w * wv;
        acc[8]  += a2.x * wv; acc[9]  += a2.y * wv; acc[10] += a2.z * wv; acc[11] += a2.w * wv;
        acc[12] += a3.x * wv; acc[13] += a3.y * wv; acc[14] += a3.z * wv; acc[15] += a3.w * wv;
    }
#pragma unroll
    for (int r = 0; r < 16; ++r) out[(size_t)(row0 + half * 16 + r) * CC + j] = acc[r];
}

// ---------------- Kernel 3b: GEMM fp32 in (layer 2) ----------------
__global__ __launch_bounds__(256) void k_gemm(const float* __restrict__ in,
                                              const float* __restrict__ w,
                                              float* __restrict__ out) {
    __shared__ float rowsT[CC * RST];
    int t = threadIdx.x;
    int row0 = blockIdx.x * 32;
    for (int it = 0; it < 16; ++it) {
        int qq = t + it * 256;
        int c = qq & 127, r = qq >> 7;
        rowsT[c * RST + r] = in[(size_t)(row0 + r) * CC + c];
    }
    __syncthreads();
    int j = t & 127, half = t >> 7;
    float acc[16];
#pragma unroll
    for (int r = 0; r < 16; ++r) acc[r] = 0.0f;
    for (int c = 0; c < CC; ++c) {
        float wv = w[c * CC + j];
        const float4* ap = (const float4*)&rowsT[c * RST + half * 16];
        float4 a0 = ap[0], a1 = ap[1], a2 = ap[2], a3 = ap[3];
        acc[0]  += a0.x * wv; acc[1]  += a0.y * wv; acc[2]  += a0.z * wv; acc[3]  += a0.w * wv;
        acc[4]  += a1.x * wv; acc[5]  += a1.y * wv; acc[6]  += a1.z * wv; acc[7]  += a1.w * wv;
        acc[8]  += a2.x * wv; acc[9]  += a2.y * wv; acc[10] += a2.z * wv; acc[11] += a2.w * wv;
        acc[12] += a3.x * wv; acc[13] += a3.y * wv; acc[14] += a3.z * wv; acc[15] += a3.w * wv;
    }
#pragma unroll
    for (int r = 0; r < 16; ++r) out[(size_t)(row0 + half * 16 + r) * CC + j] = acc[r];
}

// ---------------- Kernel 4: gather + weighted sum + bias ----------------
__global__ __launch_bounds__(256) void k_gather(const float* __restrict__ xt,
                                                const float* __restrict__ v,
                                                const int* __restrict__ idx,
                                                const float* __restrict__ bias,
                                                float* __restrict__ out) {
    int t = threadIdx.x;
    int g = blockIdx.x * 2 + (t >> 7);
    int c = t & 127;
    if (g >= ROWS_TOTAL) return;
    int b = g / NN;
    int nb = b * NN;
    float acc = bias[c];
    int base = g * KK;
#pragma unroll
    for (int k = 0; k < KK; ++k) {
        int   ii = idx[base + k];
        float vv = v[base + k];
        acc += vv * xt[(size_t)(nb + ii) * CC + c];
    }
    out[(size_t)g * CC + c] = acc;
}

// ---------------- Kernel 5: GroupNorm stats per (b, group) ----------------
__global__ __launch_bounds__(256) void k_gnstats(const float* __restrict__ xin,
                                                 float* __restrict__ stats) {
    int bg = blockIdx.x; int b = bg >> 2; int gg = bg & 3;
    size_t base = (size_t)b * (NN * CC) + gg * CPG;
    float s1 = 0.f, s2 = 0.f;
    for (int i = threadIdx.x; i < NN * CPG; i += 256) {
        float x = xin[base + (size_t)(i >> 5) * CC + (i & 31)];
        s1 += x; s2 += x * x;
    }
#pragma unroll
    for (int off = 32; off > 0; off >>= 1) { s1 += __shfl_xor(s1, off); s2 += __shfl_xor(s2, off); }
    __shared__ float r1[4], r2[4];
    int w = threadIdx.x >> 6;
    if ((threadIdx.x & 63) == 0) { r1[w] = s1; r2[w] = s2; }
    __syncthreads();
    if (threadIdx.x == 0) {
        float a = r1[0] + r1[1] + r1[2] + r1[3];
        float qq = r2[0] + r2[1] + r2[2] + r2[3];
        const float inv = 1.0f / (float)(NN * CPG);
        float mean = a * inv;
        float var = qq * inv - mean * mean;
        stats[bg * 2]     = mean;
        stats[bg * 2 + 1] = rsqrtf(fmaxf(var, 0.f) + GN_EPS);
    }
}

// ---------------- Kernel 6: GN apply + SiLU (layout-preserving, fp32 out) ----------------
__global__ __launch_bounds__(256) void k_gnsilu(const float* __restrict__ xin,
                                                const float* __restrict__ stats,
                                                const float* __restrict__ gamma,
                                                const float* __restrict__ beta,
                                                float* __restrict__ out) {
    size_t e4 = ((size_t)blockIdx.x * 256 + threadIdx.x) * 4;
    int c0 = (int)(e4 & 127);
    int b  = (int)(e4 / (NN * CC));
    int gg = c0 >> 5;
    float mean = stats[(b * 4 + gg) * 2];
    float rstd = stats[(b * 4 + gg) * 2 + 1];
    float4 x = *(const float4*)&xin[e4];
    float g0 = gamma[c0], g1 = gamma[c0 + 1], g2 = gamma[c0 + 2], g3 = gamma[c0 + 3];
    float p0 = beta[c0],  p1 = beta[c0 + 1],  p2 = beta[c0 + 2],  p3 = beta[c0 + 3];
    float y0 = (x.x - mean) * rstd * g0 + p0;
    float y1 = (x.y - mean) * rstd * g1 + p1;
    float y2 = (x.z - mean) * rstd * g2 + p2;
    float y3 = (x.w - mean) * rstd * g3 + p3;
    float4 r;
    r.x = y0 / (1.0f + expf(-y0));
    r.y = y1 / (1.0f + expf(-y1));
    r.z = y2 / (1.0f + expf(-y2));
    r.w = y3 / (1.0f + expf(-y3));
    *(float4*)&out[e4] = r;
}

// ---------------- Kernel 7: GN apply + SiLU + transpose to [B][C][N], fp32 out ----------------
__global__ __launch_bounds__(256) void k_gnsilu_out(const float* __restrict__ xin,
                                                    const float* __restrict__ stats,
                                                    const float* __restrict__ gamma,
                                                    const float* __restrict__ beta,
                                                    float* __restrict__ out) {
    __shared__ float tile[32 * 65];
    int b = blockIdx.z, ct = blockIdx.y, nt = blockIdx.x;
    int c0 = ct * 32, n0 = nt * 64;
    int t = threadIdx.x;
    int cj = t & 31, ni0 = t >> 5;
    int gg = c0 >> 5;
    float mean = stats[(b * 4 + gg) * 2];
    float rstd = stats[(b * 4 + gg) * 2 + 1];
    float gm = gamma[c0 + cj];
    float bt = beta[c0 + cj];
#pragma unroll
    for (int i = 0; i < 8; ++i) {
        int n = n0 + ni0 + i * 8;
        if (n < NN) {
            float x = xin[((size_t)b * NN + n) * CC + c0 + cj];
            float y = (x - mean) * rstd * gm + bt;
            y = y / (1.0f + expf(-y));
            tile[cj * 65 + ni0 + i * 8] = y;
        }
    }
    __syncthreads();
    int nj = t & 63, ci0 = t >> 6;
#pragma unroll
    for (int i = 0; i < 8; ++i) {
        int c = ci0 + i * 4;
        int n = n0 + nj;
        if (n < NN) out[((size_t)b * CC + c0 + c) * NN + n] = tile[c * 65 + nj];
    }
}

extern "C" void kernel_launch(void* const* d_in, const int* in_sizes, int n_in,
                              void* d_out, int out_size, void* d_ws, size_t ws_size,
                              hipStream_t stream) {
    const float* x      = (const float*)d_in[0];
    const float* w1     = (const float*)d_in[1];
    const float* b1     = (const float*)d_in[2];
    const float* w2     = (const float*)d_in[3];
    const float* b2     = (const float*)d_in[4];
    const float* gamma1 = (const float*)d_in[5];
    const float* beta1  = (const float*)d_in[6];
    const float* gamma2 = (const float*)d_in[7];
    const float* beta2  = (const float*)d_in[8];
    float* out = (float*)d_out;

    const size_t BIG = (size_t)ROWS_TOTAL * CC;   // 8,294,400
    float* ws   = (float*)d_ws;
    float* bufB = ws;                              // gemm1out -> feat2 -> gath2
    f16*   xh   = (f16*)(ws + BIG);                // f16 split hi
    f16*   xl   = xh + BIG;                        // f16 split lo
    float* bufA = ws + BIG;                        // ALIASES xh/xl; first written by gather1
    float* vbuf = ws + 2 * BIG;                    // [64800*9]
    int*   ibuf = (int*)(ws + 2 * BIG + (size_t)ROWS_TOTAL * KK);
    float* stats = ws + 2 * BIG + 2 * (size_t)ROWS_TOTAL * KK;

    k_normalize<<<ROWS_TOTAL / 4, 256, 0, stream>>>(x, xh, xl);
    k_sim_topk<<<2048, 256, 0, stream>>>(xh, xl, vbuf, ibuf);

    // layer 1 (xh/xl last read by k_gemm_hl; bufA aliases them and is written after)
    k_gemm_hl<<<(ROWS_TOTAL + 31) / 32, 256, 0, stream>>>(xh, xl, w1, bufB);
    k_gather<<<ROWS_TOTAL / 2, 256, 0, stream>>>(bufB, vbuf, ibuf, b1, bufA);
    k_gnstats<<<BN * NGROUP, 256, 0, stream>>>(bufA, stats);
    k_gnsilu<<<(int)(BIG / 1024), 256, 0, stream>>>(bufA, stats, gamma1, beta1, bufB);

    // layer 2
    k_gemm<<<(ROWS_TOTAL + 31) / 32, 256, 0, stream>>>(bufB, w2, bufA);
    k_gather<<<ROWS_TOTAL / 2, 256, 0, stream>>>(bufA, vbuf, ibuf, b2, bufB);
    k_gnstats<<<BN * NGROUP, 256, 0, stream>>>(bufB, stats);
    k_gnsilu_out<<<dim3((NN + 63) / 64, NGROUP, BN), 256, 0, stream>>>(bufB, stats, gamma2, beta2, out);
}

// Round 10
// 659.611 us; speedup vs baseline: 1.6193x; 1.0356x over previous
//
#include <hip/hip_runtime.h>
#include <hip/hip_bf16.h>

#define BN 32
#define CC 128
#define NN 2025
#define KK 9
#define NGROUP 4
#define CPG 32
#define GN_EPS 1e-5f
#define ROWS_TOTAL (BN * NN)   // 64800

typedef _Float16 f16;
typedef __attribute__((ext_vector_type(8))) _Float16 f16x8;
typedef __attribute__((ext_vector_type(4))) float f32x4;

#define S28 3.725290298461914e-09f   // 2^-28
#define S40 9.094947017729282e-13f   // 2^-40
#define RH  6.103515625e-05f         // 2^-14
#define RL  1.4901161193847656e-08f  // 2^-26

#define T0F 0.17f                    // survivor threshold (9th-best ~0.23, min ~0.19)
#define CAP 100                      // per-row survivor capacity (mean ~55, max ~95; overflow -> exact fallback)

// ---------------- Kernel 1: L2 normalize -> scaled f16 split, row-major [B*N][C] ----------------
// R10 rewrite: old version read x with stride-2025 scattered 4B loads (8.3M transactions —
// the ~26 GB/s/CU scattered-law regime proven in R0-R7). New: LDS tile transpose.
//   Phase 1: wave w loads row c=it*4+w as 64 CONTIGUOUS floats (256B/instr) -> tile[128][65]
//            (bank (c+lane)%32 -> 2/bank free).
//   Phase 2: per n, lane l reads tile[l][n], tile[l+64][n] (2/bank free) then runs the
//            EXACT same expression sequence as the old kernel (same FMA order, same
//            butterfly shuffle order, same h/l quantization, same store addresses)
//            => xh/xl bit-identical => top-9 selection cannot move (R8 lesson).
__global__ __launch_bounds__(256) void k_normalize(const float* __restrict__ x,
                                                   f16* __restrict__ xh, f16* __restrict__ xl) {
    __shared__ float tile[128][65];
    const int b  = blockIdx.y;
    const int n0 = blockIdx.x * 64;
    const int t  = threadIdx.x;
    const int w  = t >> 6;
    const int lane = t & 63;
    const int gn_ld = min(n0 + lane, NN - 1);   // tail clamp (dup value, never stored)

    // Phase 1: coalesced [128 c][64 n] tile load
    for (int it = 0; it < 32; ++it) {
        int c = it * 4 + w;
        tile[c][lane] = x[((size_t)(b * CC + c)) * NN + gn_ld];
    }
    __syncthreads();

    // Phase 2: wave w handles local n = w*16 .. w*16+15; math identical to old kernel
    for (int i = 0; i < 16; ++i) {
        int n  = w * 16 + i;
        int gn = n0 + n;
        if (gn < NN) {                      // uniform across the wave (no divergence)
            float v0 = tile[lane][n];
            float v1 = tile[lane + 64][n];
            float ss = v0 * v0 + v1 * v1;
#pragma unroll
            for (int off = 32; off > 0; off >>= 1) ss += __shfl_xor(ss, off);
            float s = 1.0f / fmaxf(sqrtf(ss), 1e-12f);
            v0 *= s; v1 *= s;
            float w0 = v0 * 16384.0f, w1 = v1 * 16384.0f;
            f16 h0 = (f16)w0, h1 = (f16)w1;
            f16 l0 = (f16)((w0 - (float)h0) * 4096.0f);
            f16 l1 = (f16)((w1 - (float)h1) * 4096.0f);
            size_t base = (size_t)(b * NN + gn) * CC;
            xh[base + lane] = h0;  xh[base + lane + 64] = h1;
            xl[base + lane] = l0;  xl[base + lane + 64] = l1;
        }
    }
}

// top-9 insert: (value desc, index asc) ordering; order-independent tie rules — EXACT
__device__ __forceinline__ void ins9(float cand, int m, float* v, int* ix,
                                     float& mv, int& mi, int& mp) {
    bool take = (cand > mv) || ((cand == mv) && (m < mi));
    if (take) {
#pragma unroll
        for (int k = 0; k < 9; ++k) if (k == mp) { v[k] = cand; ix[k] = m; }
        float nv = v[0]; int ni = ix[0]; int np = 0;
#pragma unroll
        for (int k = 1; k < 9; ++k) {
            if (v[k] < nv || (v[k] == nv && ix[k] > ni)) { nv = v[k]; ni = ix[k]; np = k; }
        }
        mv = nv; mi = ni; mp = np;
    }
}

// ---------------- Kernel 2: fused sim + top-k: LDS-staged MFMA + threshold compaction ----------------
// R9 structure FROZEN for R10 (isolate the k_normalize change).
// 272us, absmax 0.0078, FETCH 16.2MB, MFMA busy ~43us ~= the 16x16-MFMA floor (~48us).
// Known cost: SQ_LDS_BANK_CONFLICT 16.9M (~2.7 cyc/staging instr, ~30-40us) — any wave64
// b128 pattern puts >=8 dwords/bank; accepted for now.
__global__ __launch_bounds__(256) void k_sim_topk(const f16* __restrict__ xh, const f16* __restrict__ xl,
                                                  float* __restrict__ vout, int* __restrict__ iout) {
    __shared__ f16x8          stg[2][32][16];  // 16KB staged 32-m window: [hl][row][frag^(row&7)]
    __shared__ float          sv[32][CAP + 1]; // stride 101 dw; gcd(101%32=5,32)=1: conflict-free
    __shared__ unsigned short si[32][CAP + 2]; // stride 204B=51 dw; gcd(51%32=19,32)=1: conflict-free
    __shared__ int   cnt[32];
    __shared__ int   nbad;
    __shared__ int   badrows[32];

    // XCD batch-affinity swizzle (bijective over 2048): id&7 -> XCD slot -> batch b%8;
    // consecutive ids on one XCD walk r0 within the SAME batch (A-slice L2-resident).
    const int id   = blockIdx.x;                  // 0..2047
    const int b    = (id & 7) + 8 * (id >> 9);
    const int r0   = ((id >> 3) & 63) * 32;
    const int t    = threadIdx.x;
    const int w    = t >> 6;
    const int lane = t & 63;
    const int jr   = lane & 15;
    const int q    = lane >> 4;
    const int tw   = w & 1;          // which 16-row B-tile this wave owns
    const int mh   = w >> 1;         // which 16-m half of the staged window

    if (t < 32) cnt[t] = 0;
    if (t == 0) nbad = 0;

    // B fragments: wave's tile rows r0 + tw*16 + jr; lane k-window = s*32 + q*8
    f16x8 bh[4], bl[4];
    {
        int rr = b * NN + min(r0 + tw * 16 + jr, NN - 1);
        const f16* pH = xh + (size_t)rr * CC;
        const f16* pL = xl + (size_t)rr * CC;
#pragma unroll
        for (int s = 0; s < 4; ++s) {
            bh[s] = *(const f16x8*)(pH + s * 32 + q * 8);
            bl[s] = *(const f16x8*)(pL + s * 32 + q * 8);
        }
    }

    // Staging roles: thread t loads frag fi_ of window rows ri_ and ri_+16, both hl.
    const int fi_ = t & 15;
    const int ri_ = t >> 4;                 // 0..15
    const int fx  = fi_ ^ (ri_ & 7);        // swizzled frag slot ((ri_+16)&7 == ri_&7)
    const int rbuf = tw * 16 + jr;          // survivor bucket = block-local sim-row

    // preload chunk 0
    f16x8 h0r, h1r, l0r, l1r;
    {
        size_t g0 = (size_t)(b * NN + min(ri_, NN - 1)) * CC + fi_ * 8;
        size_t g1 = (size_t)(b * NN + min(ri_ + 16, NN - 1)) * CC + fi_ * 8;
        h0r = *(const f16x8*)(xh + g0);  h1r = *(const f16x8*)(xh + g1);
        l0r = *(const f16x8*)(xl + g0);  l1r = *(const f16x8*)(xl + g1);
    }

    for (int chunk = 0; chunk < 64; ++chunk) {
        __syncthreads();                     // all waves done reading previous window
        stg[0][ri_][fx]      = h0r;
        stg[0][ri_ + 16][fx] = h1r;
        stg[1][ri_][fx]      = l0r;
        stg[1][ri_ + 16][fx] = l1r;
        __syncthreads();                     // window visible
        if (chunk < 63) {                    // issue next window's loads under compute
            size_t g0 = (size_t)(b * NN + min((chunk + 1) * 32 + ri_, NN - 1)) * CC + fi_ * 8;
            size_t g1 = (size_t)(b * NN + min((chunk + 1) * 32 + ri_ + 16, NN - 1)) * CC + fi_ * 8;
            h0r = *(const f16x8*)(xh + g0);  h1r = *(const f16x8*)(xh + g1);
            l0r = *(const f16x8*)(xl + g0);  l1r = *(const f16x8*)(xl + g1);
        }
        __builtin_amdgcn_sched_barrier(0);   // keep loads issued before the MFMA cluster

        const int mb   = chunk * 32 + mh * 16;
        const int arow = mh * 16 + jr;       // lane's A row within the staged window
        const int axr  = arow & 7;
        f32x4 hh = {0.f, 0.f, 0.f, 0.f}, ll = {0.f, 0.f, 0.f, 0.f};
#pragma unroll
        for (int s = 0; s < 4; ++s) {
            f16x8 ah = stg[0][arow][(s * 4 + q) ^ axr];
            f16x8 al = stg[1][arow][(s * 4 + q) ^ axr];
            hh = __builtin_amdgcn_mfma_f32_16x16x32_f16(ah, bh[s], hh, 0, 0, 0);
            ll = __builtin_amdgcn_mfma_f32_16x16x32_f16(ah, bl[s], ll, 0, 0, 0);
            ll = __builtin_amdgcn_mfma_f32_16x16x32_f16(al, bh[s], ll, 0, 0, 0);
        }
        // threshold compaction: candidate (sim-row rbuf, m = mb + q*4 + reg) — EXACT store
#pragma unroll
        for (int reg = 0; reg < 4; ++reg) {
            int m = mb + q * 4 + reg;
            float c0 = hh[reg] * S28 + ll[reg] * S40;
            if (m < NN && c0 > T0F) {
                int pos = atomicAdd(&cnt[rbuf], 1);
                if (pos < CAP) { sv[rbuf][pos] = c0; si[rbuf][pos] = (unsigned short)m; }
            }
        }
    }
    __syncthreads();

    // Pass B: exact top-9 over survivors, one thread per row (32 rows)
    if (t < 32) {
        int r = r0 + t;
        if (r < NN) {
            int c = cnt[t];
            if (c >= 9 && c <= CAP) {
                float fv[9]; int fi[9];
#pragma unroll
                for (int k = 0; k < 9; ++k) { fv[k] = -3.0e38f; fi[k] = 0x7fffffff; }
                float mv = -3.0e38f; int mi = 0x7fffffff; int mp = 0;
                for (int j = 0; j < c; ++j) ins9(sv[t][j], (int)si[t][j], fv, fi, mv, mi, mp);
                float s = 1e-6f;
#pragma unroll
                for (int k = 0; k < 9; ++k) s += fv[k];
                float inv = 1.0f / s;
                int base = (b * NN + r) * KK;
#pragma unroll
                for (int k = 0; k < 9; ++k) { vout[base + k] = fv[k] * inv; iout[base + k] = fi[k]; }
            } else {
                int slot = atomicAdd(&nbad, 1);
                badrows[slot] = r;
            }
        }
    }
    __syncthreads();

    // Fallback: wave 0 exactly re-solves any bad rows (expected: none)
    if (w == 0) {
        int nb = nbad;
        for (int ib = 0; ib < nb; ++ib) {
            int r = badrows[ib];
            const f16* rH = xh + ((size_t)b * NN + r) * CC;
            const f16* rL = xl + ((size_t)b * NN + r) * CC;
            float fv[9]; int fi[9];
#pragma unroll
            for (int k = 0; k < 9; ++k) { fv[k] = -3.0e38f; fi[k] = 0x7fffffff; }
            float mv = -3.0e38f; int mi = 0x7fffffff; int mp = 0;
            for (int m = lane; m < NN; m += 64) {
                const f16* mH = xh + ((size_t)b * NN + m) * CC;
                const f16* mL = xl + ((size_t)b * NN + m) * CC;
                float a1 = 0.f, a2 = 0.f;
                for (int c2 = 0; c2 < CC; ++c2) {
                    float hr = (float)rH[c2], hm = (float)mH[c2];
                    float lr = (float)rL[c2], lm = (float)mL[c2];
                    a1 += hr * hm;
                    a2 += hr * lm + lr * hm;
                }
                ins9(a1 * S28 + a2 * S40, m, fv, fi, mv, mi, mp);
            }
#pragma unroll
            for (int off = 1; off < 64; off <<= 1) {
                float pv[9]; int pi[9];
#pragma unroll
                for (int k = 0; k < 9; ++k) { pv[k] = __shfl_xor(fv[k], off); pi[k] = __shfl_xor(fi[k], off); }
#pragma unroll
                for (int k = 0; k < 9; ++k) ins9(pv[k], pi[k], fv, fi, mv, mi, mp);
            }
            if (lane == 0) {
                float s = 1e-6f;
#pragma unroll
                for (int k = 0; k < 9; ++k) s += fv[k];
                float inv = 1.0f / s;
                int base = (b * NN + r) * KK;
#pragma unroll
                for (int k = 0; k < 9; ++k) { vout[base + k] = fv[k] * inv; iout[base + k] = fi[k]; }
            }
        }
    }
}

// ---------------- Kernel 3a: GEMM out = reconstruct(xh,xl) @ w  (layer 1) ----------------
#define RST 36
__global__ __launch_bounds__(256) void k_gemm_hl(const f16* __restrict__ xh, const f16* __restrict__ xl,
                                                 const float* __restrict__ w, float* __restrict__ out) {
    __shared__ float rowsT[CC * RST];
    int t = threadIdx.x;
    int row0 = blockIdx.x * 32;
    for (int it = 0; it < 16; ++it) {
        int qq = t + it * 256;
        int c = qq & 127, r = qq >> 7;
        size_t idx = (size_t)(row0 + r) * CC + c;
        rowsT[c * RST + r] = (float)xh[idx] * RH + (float)xl[idx] * RL;
    }
    __syncthreads();
    int j = t & 127, half = t >> 7;
    float acc[16];
#pragma unroll
    for (int r = 0; r < 16; ++r) acc[r] = 0.0f;
    for (int c = 0; c < CC; ++c) {
        float wv = w[c * CC + j];
        const float4* ap = (const float4*)&rowsT[c * RST + half * 16];
        float4 a0 = ap[0], a1 = ap[1], a2 = ap[2], a3 = ap[3];
        acc[0]  += a0.x * wv; acc[1]  += a0.y * wv; acc[2]  += a0.z * wv; acc[3]  += a0.w * wv;
        acc[4]  += a1.x * wv; acc[5]  += a1.y * wv; acc[6]  += a1.z * wv; acc[7]  += a1.w * wv;
        acc[8]  += a2.x * wv; acc[9]  += a2.y * wv; acc[10] += a2.z * wv; acc[11] += a2.w * wv;
        acc[12] += a3.x * wv; acc[13] += a3.y * wv; acc[14] += a3.z * wv; acc[15] += a3.w * wv;
    }
#pragma unroll
    for (int r = 0; r < 16; ++r) out[(size_t)(row0 + half * 16 + r) * CC + j] = acc[r];
}

// ---------------- Kernel 3b: GEMM fp32 in (layer 2) ----------------
__global__ __launch_bounds__(256) void k_gemm(const float* __restrict__ in,
                                              const float* __restrict__ w,
                                              float* __restrict__ out) {
    __shared__ float rowsT[CC * RST];
    int t = threadIdx.x;
    int row0 = blockIdx.x * 32;
    for (int it = 0; it < 16; ++it) {
        int qq = t + it * 256;
        int c = qq & 127, r = qq >> 7;
        rowsT[c * RST + r] = in[(size_t)(row0 + r) * CC + c];
    }
    __syncthreads();
    int j = t & 127, half = t >> 7;
    float acc[16];
#pragma unroll
    for (int r = 0; r < 16; ++r) acc[r] = 0.0f;
    for (int c = 0; c < CC; ++c) {
        float wv = w[c * CC + j];
        const float4* ap = (const float4*)&rowsT[c * RST + half * 16];
        float4 a0 = ap[0], a1 = ap[1], a2 = ap[2], a3 = ap[3];
        acc[0]  += a0.x * wv; acc[1]  += a0.y * wv; acc[2]  += a0.z * wv; acc[3]  += a0.w * wv;
        acc[4]  += a1.x * wv; acc[5]  += a1.y * wv; acc[6]  += a1.z * wv; acc[7]  += a1.w * wv;
        acc[8]  += a2.x * wv; acc[9]  += a2.y * wv; acc[10] += a2.z * wv; acc[11] += a2.w * wv;
        acc[12] += a3.x * wv; acc[13] += a3.y * wv; acc[14] += a3.z * wv; acc[15] += a3.w * wv;
    }
#pragma unroll
    for (int r = 0; r < 16; ++r) out[(size_t)(row0 + half * 16 + r) * CC + j] = acc[r];
}

// ---------------- Kernel 4: gather + weighted sum + bias ----------------
__global__ __launch_bounds__(256) void k_gather(const float* __restrict__ xt,
                                                const float* __restrict__ v,
                                                const int* __restrict__ idx,
                                                const float* __restrict__ bias,
                                                float* __restrict__ out) {
    int t = threadIdx.x;
    int g = blockIdx.x * 2 + (t >> 7);
    int c = t & 127;
    if (g >= ROWS_TOTAL) return;
    int b = g / NN;
    int nb = b * NN;
    float acc = bias[c];
    int base = g * KK;
#pragma unroll
    for (int k = 0; k < KK; ++k) {
        int   ii = idx[base + k];
        float vv = v[base + k];
        acc += vv * xt[(size_t)(nb + ii) * CC + c];
    }
    out[(size_t)g * CC + c] = acc;
}

// ---------------- Kernel 5: GroupNorm stats per (b, group) ----------------
__global__ __launch_bounds__(256) void k_gnstats(const float* __restrict__ xin,
                                                 float* __restrict__ stats) {
    int bg = blockIdx.x; int b = bg >> 2; int gg = bg & 3;
    size_t base = (size_t)b * (NN * CC) + gg * CPG;
    float s1 = 0.f, s2 = 0.f;
    for (int i = threadIdx.x; i < NN * CPG; i += 256) {
        float x = xin[base + (size_t)(i >> 5) * CC + (i & 31)];
        s1 += x; s2 += x * x;
    }
#pragma unroll
    for (int off = 32; off > 0; off >>= 1) { s1 += __shfl_xor(s1, off); s2 += __shfl_xor(s2, off); }
    __shared__ float r1[4], r2[4];
    int w = threadIdx.x >> 6;
    if ((threadIdx.x & 63) == 0) { r1[w] = s1; r2[w] = s2; }
    __syncthreads();
    if (threadIdx.x == 0) {
        float a = r1[0] + r1[1] + r1[2] + r1[3];
        float qq = r2[0] + r2[1] + r2[2] + r2[3];
        const float inv = 1.0f / (float)(NN * CPG);
        float mean = a * inv;
        float var = qq * inv - mean * mean;
        stats[bg * 2]     = mean;
        stats[bg * 2 + 1] = rsqrtf(fmaxf(var, 0.f) + GN_EPS);
    }
}

// ---------------- Kernel 6: GN apply + SiLU (layout-preserving, fp32 out) ----------------
__global__ __launch_bounds__(256) void k_gnsilu(const float* __restrict__ xin,
                                                const float* __restrict__ stats,
                                                const float* __restrict__ gamma,
                                                const float* __restrict__ beta,
                                                float* __restrict__ out) {
    size_t e4 = ((size_t)blockIdx.x * 256 + threadIdx.x) * 4;
    int c0 = (int)(e4 & 127);
    int b  = (int)(e4 / (NN * CC));
    int gg = c0 >> 5;
    float mean = stats[(b * 4 + gg) * 2];
    float rstd = stats[(b * 4 + gg) * 2 + 1];
    float4 x = *(const float4*)&xin[e4];
    float g0 = gamma[c0], g1 = gamma[c0 + 1], g2 = gamma[c0 + 2], g3 = gamma[c0 + 3];
    float p0 = beta[c0],  p1 = beta[c0 + 1],  p2 = beta[c0 + 2],  p3 = beta[c0 + 3];
    float y0 = (x.x - mean) * rstd * g0 + p0;
    float y1 = (x.y - mean) * rstd * g1 + p1;
    float y2 = (x.z - mean) * rstd * g2 + p2;
    float y3 = (x.w - mean) * rstd * g3 + p3;
    float4 r;
    r.x = y0 / (1.0f + expf(-y0));
    r.y = y1 / (1.0f + expf(-y1));
    r.z = y2 / (1.0f + expf(-y2));
    r.w = y3 / (1.0f + expf(-y3));
    *(float4*)&out[e4] = r;
}

// ---------------- Kernel 7: GN apply + SiLU + transpose to [B][C][N], fp32 out ----------------
__global__ __launch_bounds__(256) void k_gnsilu_out(const float* __restrict__ xin,
                                                    const float* __restrict__ stats,
                                                    const float* __restrict__ gamma,
                                                    const float* __restrict__ beta,
                                                    float* __restrict__ out) {
    __shared__ float tile[32 * 65];
    int b = blockIdx.z, ct = blockIdx.y, nt = blockIdx.x;
    int c0 = ct * 32, n0 = nt * 64;
    int t = threadIdx.x;
    int cj = t & 31, ni0 = t >> 5;
    int gg = c0 >> 5;
    float mean = stats[(b * 4 + gg) * 2];
    float rstd = stats[(b * 4 + gg) * 2 + 1];
    float gm = gamma[c0 + cj];
    float bt = beta[c0 + cj];
#pragma unroll
    for (int i = 0; i < 8; ++i) {
        int n = n0 + ni0 + i * 8;
        if (n < NN) {
            float x = xin[((size_t)b * NN + n) * CC + c0 + cj];
            float y = (x - mean) * rstd * gm + bt;
            y = y / (1.0f + expf(-y));
            tile[cj * 65 + ni0 + i * 8] = y;
        }
    }
    __syncthreads();
    int nj = t & 63, ci0 = t >> 6;
#pragma unroll
    for (int i = 0; i < 8; ++i) {
        int c = ci0 + i * 4;
        int n = n0 + nj;
        if (n < NN) out[((size_t)b * CC + c0 + c) * NN + n] = tile[c * 65 + nj];
    }
}

extern "C" void kernel_launch(void* const* d_in, const int* in_sizes, int n_in,
                              void* d_out, int out_size, void* d_ws, size_t ws_size,
                              hipStream_t stream) {
    const float* x      = (const float*)d_in[0];
    const float* w1     = (const float*)d_in[1];
    const float* b1     = (const float*)d_in[2];
    const float* w2     = (const float*)d_in[3];
    const float* b2     = (const float*)d_in[4];
    const float* gamma1 = (const float*)d_in[5];
    const float* beta1  = (const float*)d_in[6];
    const float* gamma2 = (const float*)d_in[7];
    const float* beta2  = (const float*)d_in[8];
    float* out = (float*)d_out;

    const size_t BIG = (size_t)ROWS_TOTAL * CC;   // 8,294,400
    float* ws   = (float*)d_ws;
    float* bufB = ws;                              // gemm1out -> feat2 -> gath2
    f16*   xh   = (f16*)(ws + BIG);                // f16 split hi
    f16*   xl   = xh + BIG;                        // f16 split lo
    float* bufA = ws + BIG;                        // ALIASES xh/xl; first written by gather1
    float* vbuf = ws + 2 * BIG;                    // [64800*9]
    int*   ibuf = (int*)(ws + 2 * BIG + (size_t)ROWS_TOTAL * KK);
    float* stats = ws + 2 * BIG + 2 * (size_t)ROWS_TOTAL * KK;

    k_normalize<<<dim3(32, BN), 256, 0, stream>>>(x, xh, xl);
    k_sim_topk<<<2048, 256, 0, stream>>>(xh, xl, vbuf, ibuf);

    // layer 1 (xh/xl last read by k_gemm_hl; bufA aliases them and is written after)
    k_gemm_hl<<<(ROWS_TOTAL + 31) / 32, 256, 0, stream>>>(xh, xl, w1, bufB);
    k_gather<<<ROWS_TOTAL / 2, 256, 0, stream>>>(bufB, vbuf, ibuf, b1, bufA);
    k_gnstats<<<BN * NGROUP, 256, 0, stream>>>(bufA, stats);
    k_gnsilu<<<(int)(BIG / 1024), 256, 0, stream>>>(bufA, stats, gamma1, beta1, bufB);

    // layer 2
    k_gemm<<<(ROWS_TOTAL + 31) / 32, 256, 0, stream>>>(bufB, w2, bufA);
    k_gather<<<ROWS_TOTAL / 2, 256, 0, stream>>>(bufA, vbuf, ibuf, b2, bufB);
    k_gnstats<<<BN * NGROUP, 256, 0, stream>>>(bufB, stats);
    k_gnsilu_out<<<dim3((NN + 63) / 64, NGROUP, BN), 256, 0, stream>>>(bufB, stats, gamma2, beta2, out);
}